// Round 1
// baseline (3947.554 us; speedup 1.0000x reference)
//
#include <hip/hip_runtime.h>
#include <hip/hip_bf16.h>
#include <math.h>

// Problem constants
#define S_LEN 2048
#define H_DIM 2048
#define NH 16
#define DN 128
#define DR 64
#define DV 128
#define QL 1536
#define KL 512
#define FUSED_N (QL + KL + DR)      // 2112
#define QB_N (NH * (DN + DR))       // 3072
#define KVB_N (NH * (DN + DV))      // 4096
#define HD_QK (DN + DR)             // 192
#define EPS_RMS 1e-6f

// ---------------------------------------------------------------------------
// Generic fp32 tiled GEMM: C[M,N] = A[M,K] @ B[K,N], row-major, all dims
// divisible by tile sizes (verified for every call site in this problem).
// 64x64 tile, BK=16, 256 threads, 4x4 micro-tile per thread.
// ---------------------------------------------------------------------------
#define BM 64
#define BN 64
#define BKK 16

__global__ __launch_bounds__(256) void gemm_f32(
    const float* __restrict__ A, const float* __restrict__ B,
    float* __restrict__ C, int M, int N, int K)
{
    __shared__ float As[BKK][BM + 1];
    __shared__ float Bs[BKK][BN + 1];

    const int tid = threadIdx.x;
    const int tx = tid & 15;        // 0..15  (N direction)
    const int ty = tid >> 4;        // 0..15  (M direction)
    const int bm = blockIdx.y * BM;
    const int bn = blockIdx.x * BN;

    float acc[4][4] = {};

    for (int k0 = 0; k0 < K; k0 += BKK) {
        // Load A tile (BM x BKK) into As[k][m]
        #pragma unroll
        for (int i = 0; i < (BM * BKK) / 256; ++i) {
            int idx = tid + i * 256;
            int m = idx >> 4;           // idx / BKK
            int kk = idx & 15;          // idx % BKK
            As[kk][m] = A[(size_t)(bm + m) * K + k0 + kk];
        }
        // Load B tile (BKK x BN) into Bs[k][n]
        #pragma unroll
        for (int i = 0; i < (BKK * BN) / 256; ++i) {
            int idx = tid + i * 256;
            int kk = idx >> 6;          // idx / BN
            int n = idx & 63;           // idx % BN
            Bs[kk][n] = B[(size_t)(k0 + kk) * N + bn + n];
        }
        __syncthreads();

        #pragma unroll
        for (int kk = 0; kk < BKK; ++kk) {
            float a[4], b[4];
            #pragma unroll
            for (int i = 0; i < 4; ++i) a[i] = As[kk][ty * 4 + i];
            #pragma unroll
            for (int j = 0; j < 4; ++j) b[j] = Bs[kk][tx * 4 + j];
            #pragma unroll
            for (int i = 0; i < 4; ++i)
                #pragma unroll
                for (int j = 0; j < 4; ++j)
                    acc[i][j] = fmaf(a[i], b[j], acc[i][j]);
        }
        __syncthreads();
    }

    #pragma unroll
    for (int i = 0; i < 4; ++i)
        #pragma unroll
        for (int j = 0; j < 4; ++j)
            C[(size_t)(bm + ty * 4 + i) * N + bn + tx * 4 + j] = acc[i][j];
}

// ---------------------------------------------------------------------------
// RMSNorm over rows: out[row, 0:ncols] = x * gamma * rsqrt(mean(x^2)+eps)
// in is strided (view into fused buffer); out is compact.
// ---------------------------------------------------------------------------
__global__ __launch_bounds__(256) void rmsnorm_k(
    const float* __restrict__ in, int stride, int ncols,
    const float* __restrict__ gamma, float* __restrict__ out)
{
    const int row = blockIdx.x;
    const float* x = in + (size_t)row * stride;

    float ss = 0.f;
    for (int c = threadIdx.x; c < ncols; c += 256) {
        float v = x[c];
        ss += v * v;
    }
    #pragma unroll
    for (int off = 32; off > 0; off >>= 1) ss += __shfl_down(ss, off);

    __shared__ float warp_s[4];
    __shared__ float scale_s;
    const int wid = threadIdx.x >> 6;
    if ((threadIdx.x & 63) == 0) warp_s[wid] = ss;
    __syncthreads();
    if (threadIdx.x == 0) {
        float t = warp_s[0] + warp_s[1] + warp_s[2] + warp_s[3];
        scale_s = rsqrtf(t / (float)ncols + EPS_RMS);
    }
    __syncthreads();
    const float sc = scale_s;
    for (int c = threadIdx.x; c < ncols; c += 256)
        out[(size_t)row * ncols + c] = x[c] * gamma[c] * sc;
}

// ---------------------------------------------------------------------------
// RoPE. cos/sin computed on the fly:
//   invf[j] = 10000^(-j/32), j = d & 31 ; ang = pos * invf
//   d < 32 : out = x[d]*cos - x[d+32]*sin
//   d >= 32: out = x[d]*cos + x[d-32]*sin
// ---------------------------------------------------------------------------
__device__ __forceinline__ void rope_pair(int s, int d, float x, float other,
                                          float* outv)
{
    const int j = d & 31;
    // 10000^(-j/32) = exp(-j * ln(10000)/32)
    const float invf = expf(-0.28782313662425572f * (float)j);
    const float ang = (float)s * invf;
    float sn, cs;
    sincosf(ang, &sn, &cs);
    float rot = (d < 32) ? -other : other;
    *outv = x * cs + rot * sn;
}

// In-place RoPE on q_pe: q layout [S][NH][192], last 64 of each head.
__global__ void rope_q_k(float* __restrict__ q)
{
    const int s = blockIdx.x;
    const int h = blockIdx.y;
    const int d = threadIdx.x;              // 0..63
    float* base = q + (size_t)s * QB_N + h * HD_QK + DN;
    float x = base[d];
    float other = (d < 32) ? base[d + 32] : base[d - 32];
    __syncthreads();
    float o;
    rope_pair(s, d, x, other, &o);
    base[d] = o;
}

// Out-of-place RoPE on k_pe: src = fused[:, QL+KL : QL+KL+64] -> kpe[S][64]
__global__ void rope_kpe_k(const float* __restrict__ fused,
                           float* __restrict__ kpe)
{
    const int s = blockIdx.x;
    const int d = threadIdx.x;              // 0..63
    const float* src = fused + (size_t)s * FUSED_N + (QL + KL);
    float x = src[d];
    float other = (d < 32) ? src[d + 32] : src[d - 32];
    float o;
    rope_pair(s, d, x, other, &o);
    kpe[(size_t)s * DR + d] = o;
}

// ---------------------------------------------------------------------------
// Flash attention (causal), fp32, online softmax.
// grid: (S/BQ, NH).  block: 256.
// q   : [S][NH][192]  (q_pe already rotated in place -> contiguous q_full)
// kv  : [S][NH][256]  (first 128 = k_nope, last 128 = v)
// kpe : [S][64]       (rotated, shared across heads)
// attn: [S][NH*128]
// ---------------------------------------------------------------------------
#define BQ 16
#define BKA 32

__global__ __launch_bounds__(256) void attn_fa_k(
    const float* __restrict__ q, const float* __restrict__ kv,
    const float* __restrict__ kpe, float* __restrict__ attn)
{
    __shared__ float Qs[BQ][HD_QK + 1];     // 16 x 193
    __shared__ float Ks[BKA][HD_QK + 1];    // 32 x 193
    __shared__ float Vs[BKA][DV + 1];       // 32 x 129
    __shared__ float Ss[BQ][BKA];           // 16 x 32
    __shared__ float Os[BQ][DV + 1];        // 16 x 129
    __shared__ float ms[BQ], ls[BQ], as_[BQ];

    const int tid = threadIdx.x;
    const int q0 = blockIdx.x * BQ;
    const int h = blockIdx.y;
    const float scale = 0.07216878364870323f;   // 1/sqrt(192)

    // Load Q tile
    for (int i = tid; i < BQ * HD_QK; i += 256) {
        int r = i / HD_QK, c = i % HD_QK;
        Qs[r][c] = q[(size_t)(q0 + r) * QB_N + h * HD_QK + c];
    }
    for (int i = tid; i < BQ * DV; i += 256) Os[i / DV][i % DV] = 0.f;
    if (tid < BQ) { ms[tid] = -1e30f; ls[tid] = 0.f; }
    __syncthreads();

    const int nk = q0 + BQ;                     // causal key bound
    const int nkt = (nk + BKA - 1) / BKA;

    for (int kt = 0; kt < nkt; ++kt) {
        const int k0 = kt * BKA;
        // Load K tile (k_nope ++ k_pe) and V tile
        for (int i = tid; i < BKA * HD_QK; i += 256) {
            int r = i / HD_QK, c = i % HD_QK;
            Ks[r][c] = (c < DN)
                ? kv[(size_t)(k0 + r) * KVB_N + h * (DN + DV) + c]
                : kpe[(size_t)(k0 + r) * DR + (c - DN)];
        }
        for (int i = tid; i < BKA * DV; i += 256) {
            int r = i / DV, c = i % DV;
            Vs[r][c] = kv[(size_t)(k0 + r) * KVB_N + h * (DN + DV) + DN + c];
        }
        __syncthreads();

        // Scores: 16x32 = 512, 2 per thread
        for (int e = tid; e < BQ * BKA; e += 256) {
            int r = e / BKA, c = e % BKA;
            float s = 0.f;
            #pragma unroll 8
            for (int dd = 0; dd < HD_QK; ++dd) s = fmaf(Qs[r][dd], Ks[c][dd], s);
            s *= scale;
            if (k0 + c > q0 + r) s = -1e30f;
            Ss[r][c] = s;
        }
        __syncthreads();

        // Online softmax bookkeeping (one thread per row)
        if (tid < BQ) {
            const int r = tid;
            float m = ms[r];
            #pragma unroll
            for (int c = 0; c < BKA; ++c) m = fmaxf(m, Ss[r][c]);
            float a = expf(ms[r] - m);
            float lsum = 0.f;
            #pragma unroll
            for (int c = 0; c < BKA; ++c) {
                float p = expf(Ss[r][c] - m);
                Ss[r][c] = p;
                lsum += p;
            }
            ls[r] = ls[r] * a + lsum;
            ms[r] = m;
            as_[r] = a;
        }
        __syncthreads();

        // O update: 16x128 = 2048, 8 per thread
        for (int e = tid; e < BQ * DV; e += 256) {
            int r = e / DV, d = e % DV;
            float o = Os[r][d] * as_[r];
            #pragma unroll
            for (int c = 0; c < BKA; ++c) o = fmaf(Ss[r][c], Vs[c][d], o);
            Os[r][d] = o;
        }
        __syncthreads();
    }

    for (int e = tid; e < BQ * DV; e += 256) {
        int r = e / DV, d = e % DV;
        attn[(size_t)(q0 + r) * (NH * DV) + h * DV + d] = Os[r][d] / ls[r];
    }
}

// ---------------------------------------------------------------------------
// Launch
// ---------------------------------------------------------------------------
extern "C" void kernel_launch(void* const* d_in, const int* in_sizes, int n_in,
                              void* d_out, int out_size, void* d_ws, size_t ws_size,
                              hipStream_t stream)
{
    const float* hidden   = (const float*)d_in[0];   // [S][H]
    const float* w_kv_a   = (const float*)d_in[1];   // [H][2112]
    const float* q_gamma  = (const float*)d_in[2];   // [1536]
    const float* w_qb     = (const float*)d_in[3];   // [1536][3072]
    const float* kv_gamma = (const float*)d_in[4];   // [512]
    const float* w_kvb    = (const float*)d_in[5];   // [512][4096]
    const float* w_o      = (const float*)d_in[6];   // [2048][2048]
    float* out = (float*)d_out;                      // [S][H]

    // Workspace layout (floats)
    float* ws = (float*)d_ws;
    float* fused = ws;                               // [S][2112]
    float* q_n   = fused + (size_t)S_LEN * FUSED_N;  // [S][1536]
    float* qbuf  = q_n   + (size_t)S_LEN * QL;       // [S][3072]
    float* kv_n  = qbuf  + (size_t)S_LEN * QB_N;     // [S][512]
    float* kvbuf = kv_n  + (size_t)S_LEN * KL;       // [S][4096]
    float* kpe   = kvbuf + (size_t)S_LEN * KVB_N;    // [S][64]
    float* attn  = kpe   + (size_t)S_LEN * DR;       // [S][2048]

    dim3 blk(256);

    // 1. fused = hidden @ w_kv_a      (2048 x 2048 x 2112)
    gemm_f32<<<dim3(FUSED_N / BN, S_LEN / BM), blk, 0, stream>>>(
        hidden, w_kv_a, fused, S_LEN, FUSED_N, H_DIM);

    // 2. q_n = rmsnorm(fused[:, :1536]) ; kv_n = rmsnorm(fused[:, 1536:2048])
    rmsnorm_k<<<S_LEN, blk, 0, stream>>>(fused, FUSED_N, QL, q_gamma, q_n);
    rmsnorm_k<<<S_LEN, blk, 0, stream>>>(fused + QL, FUSED_N, KL, kv_gamma, kv_n);

    // 3. q = q_n @ w_qb               (2048 x 1536 x 3072)
    gemm_f32<<<dim3(QB_N / BN, S_LEN / BM), blk, 0, stream>>>(
        q_n, w_qb, qbuf, S_LEN, QB_N, QL);

    // 4. kv = kv_n @ w_kvb            (2048 x 512 x 4096)
    gemm_f32<<<dim3(KVB_N / BN, S_LEN / BM), blk, 0, stream>>>(
        kv_n, w_kvb, kvbuf, S_LEN, KVB_N, KL);

    // 5. RoPE
    rope_q_k<<<dim3(S_LEN, NH), dim3(64), 0, stream>>>(qbuf);
    rope_kpe_k<<<dim3(S_LEN), dim3(64), 0, stream>>>(fused, kpe);

    // 6. Flash attention
    attn_fa_k<<<dim3(S_LEN / BQ, NH), blk, 0, stream>>>(qbuf, kvbuf, kpe, attn);

    // 7. out = attn @ w_o             (2048 x 2048 x 2048)
    gemm_f32<<<dim3(H_DIM / BN, S_LEN / BM), blk, 0, stream>>>(
        attn, w_o, out, S_LEN, H_DIM, H_DIM);
}

// Round 3
// 1429.307 us; speedup vs baseline: 2.7619x; 2.7619x over previous
//
#include <hip/hip_runtime.h>
#include <math.h>

#define S_LEN 2048
#define NH 16
#define DN 128
#define DR 64
#define DV 128
#define QL 1536
#define KL 512
#define FUSED_N 2112
#define FPAD 2176            // fused padded to 17*128 for uniform GEMM tiles
#define QB_N 3072
#define KVB_N 4096
#define HD_QK 192
#define EPS_RMS 1e-6f

typedef _Float16 f16;
typedef _Float16 half8 __attribute__((ext_vector_type(8)));
typedef _Float16 half4 __attribute__((ext_vector_type(4)));
typedef float floatx4 __attribute__((ext_vector_type(4)));

// ---------------------------------------------------------------------------
// fp32 -> f16 elementwise (4/thread)
// ---------------------------------------------------------------------------
__global__ __launch_bounds__(256) void cvt_f16_k(const float* __restrict__ in,
                                                 f16* __restrict__ out, int n4)
{
    int i = blockIdx.x * 256 + threadIdx.x;
    if (i < n4) {
        float4 v = ((const float4*)in)[i];
        half4 h;
        h[0] = (f16)v.x; h[1] = (f16)v.y; h[2] = (f16)v.z; h[3] = (f16)v.w;
        ((half4*)out)[i] = h;
    }
}

// ---------------------------------------------------------------------------
// fp32 [K][N] -> f16 B^T [Npad][K]; rows n>=N zero-filled.
// grid (Npad/32, K/32), 256 threads, 32x32 tile via LDS.
// ---------------------------------------------------------------------------
__global__ __launch_bounds__(256) void tconv_k(const float* __restrict__ in,
                                               f16* __restrict__ out,
                                               int K, int N)
{
    __shared__ float t[32][33];
    const int k0 = blockIdx.y * 32, n0 = blockIdx.x * 32;
    const int c = threadIdx.x & 31, r8 = threadIdx.x >> 5;
    #pragma unroll
    for (int i = 0; i < 4; ++i) {
        int r = r8 + i * 8;
        int gc = n0 + c;
        t[r][c] = (gc < N) ? in[(size_t)(k0 + r) * N + gc] : 0.f;
    }
    __syncthreads();
    #pragma unroll
    for (int i = 0; i < 4; ++i) {
        int r = r8 + i * 8;     // local n
        out[(size_t)(n0 + r) * K + k0 + c] = (f16)t[c][r];
    }
}

// ---------------------------------------------------------------------------
// f16 MFMA GEMM: C[M,N] = A[M,K] @ Bt[N,K]^T.  128x128 tile, BK=64,
// 256 threads = 4 waves in 2x2, each wave 4x4 grid of 16x16x32 MFMAs.
// Staging via global_load_lds width 16; LDS chunks XOR-swizzled so the
// unpadded 128-B rows read back conflict-free (2-way max) as ds_read_b128.
// ---------------------------------------------------------------------------
__device__ __forceinline__ void async16(const f16* gp, f16* lp)
{
    __builtin_amdgcn_global_load_lds(
        (const __attribute__((address_space(1))) void*)gp,
        (__attribute__((address_space(3))) void*)lp, 16, 0, 0);
}

template <int OUT_F16>
__global__ __launch_bounds__(256) void gemm_mfma(
    const f16* __restrict__ A,   // [M][K]
    const f16* __restrict__ Bt,  // [N][K]
    void* __restrict__ Cv, int M, int N, int K)
{
    __shared__ f16 As[128 * 64];
    __shared__ f16 Bs[128 * 64];

    const int tid = threadIdx.x;
    const int wv = tid >> 6, lane = tid & 63;
    const int quad = lane >> 4, l15 = lane & 15;
    const int wr = wv >> 1, wc = wv & 1;
    const int bm = blockIdx.y * 128, bn = blockIdx.x * 128;
    const int srow = lane >> 3;      // 0..7
    const int sc = lane & 7;         // slot chunk 0..7

    floatx4 acc[4][4] = {};

    for (int k0 = 0; k0 < K; k0 += 64) {
        #pragma unroll
        for (int t = 0; t < 4; ++t) {
            int rl = wv * 32 + t * 8 + srow;     // local row 0..127
            int ch = sc ^ (rl & 7);              // data chunk for this slot
            async16(A  + (size_t)(bm + rl) * K + k0 + ch * 8,
                    &As[(wv * 32 + t * 8) * 64]);
            async16(Bt + (size_t)(bn + rl) * K + k0 + ch * 8,
                    &Bs[(wv * 32 + t * 8) * 64]);
        }
        __syncthreads();

        #pragma unroll
        for (int ks = 0; ks < 2; ++ks) {
            half8 av[4], bv[4];
            #pragma unroll
            for (int i = 0; i < 4; ++i) {
                int m = wr * 64 + i * 16 + l15;
                av[i] = *(const half8*)&As[m * 64 + ((ks * 4 + quad) ^ (m & 7)) * 8];
            }
            #pragma unroll
            for (int j = 0; j < 4; ++j) {
                int n = wc * 64 + j * 16 + l15;
                bv[j] = *(const half8*)&Bs[n * 64 + ((ks * 4 + quad) ^ (n & 7)) * 8];
            }
            #pragma unroll
            for (int i = 0; i < 4; ++i)
                #pragma unroll
                for (int j = 0; j < 4; ++j)
                    acc[i][j] = __builtin_amdgcn_mfma_f32_16x16x32_f16(
                        av[i], bv[j], acc[i][j], 0, 0, 0);
        }
        __syncthreads();
    }

    // C/D layout: col = lane&15, row = quad*4 + reg
    #pragma unroll
    for (int i = 0; i < 4; ++i) {
        int rbase = bm + wr * 64 + i * 16 + quad * 4;
        #pragma unroll
        for (int j = 0; j < 4; ++j) {
            int cidx = bn + wc * 64 + j * 16 + l15;
            #pragma unroll
            for (int rr = 0; rr < 4; ++rr) {
                if (OUT_F16)
                    ((f16*)Cv)[(size_t)(rbase + rr) * N + cidx] = (f16)acc[i][j][rr];
                else
                    ((float*)Cv)[(size_t)(rbase + rr) * N + cidx] = acc[i][j][rr];
            }
        }
    }
}

// ---------------------------------------------------------------------------
// RMSNorm: fp32 strided in -> f16 compact out
// ---------------------------------------------------------------------------
__global__ __launch_bounds__(256) void rmsnorm_k(
    const float* __restrict__ in, int stride, int ncols,
    const float* __restrict__ gamma, f16* __restrict__ out)
{
    const int row = blockIdx.x;
    const float* x = in + (size_t)row * stride;

    float ss = 0.f;
    for (int c = threadIdx.x; c < ncols; c += 256) {
        float v = x[c];
        ss += v * v;
    }
    #pragma unroll
    for (int off = 32; off > 0; off >>= 1) ss += __shfl_down(ss, off);

    __shared__ float warp_s[4];
    __shared__ float scale_s;
    const int wid = threadIdx.x >> 6;
    if ((threadIdx.x & 63) == 0) warp_s[wid] = ss;
    __syncthreads();
    if (threadIdx.x == 0) {
        float t = warp_s[0] + warp_s[1] + warp_s[2] + warp_s[3];
        scale_s = rsqrtf(t / (float)ncols + EPS_RMS);
    }
    __syncthreads();
    const float sc = scale_s;
    for (int c = threadIdx.x; c < ncols; c += 256)
        out[(size_t)row * ncols + c] = (f16)(x[c] * gamma[c] * sc);
}

// ---------------------------------------------------------------------------
// RoPE
// ---------------------------------------------------------------------------
__device__ __forceinline__ float rope_one(int s, int d, float x, float other)
{
    const int j = d & 31;
    const float invf = expf(-0.28782313662425572f * (float)j); // 10000^(-j/32)
    const float ang = (float)s * invf;
    float sn, cs;
    sincosf(ang, &sn, &cs);
    float rot = (d < 32) ? -other : other;
    return x * cs + rot * sn;
}

__global__ void rope_q_k(f16* __restrict__ q)
{
    const int s = blockIdx.x, h = blockIdx.y, d = threadIdx.x; // d 0..63
    f16* base = q + (size_t)s * QB_N + h * HD_QK + DN;
    float x = (float)base[d];
    float other = (float)((d < 32) ? base[d + 32] : base[d - 32]);
    __syncthreads();
    base[d] = (f16)rope_one(s, d, x, other);
}

__global__ void rope_kpe_k(const float* __restrict__ fused, f16* __restrict__ kpe)
{
    const int s = blockIdx.x, d = threadIdx.x;
    const float* src = fused + (size_t)s * FPAD + (QL + KL);
    float x = src[d];
    float other = (d < 32) ? src[d + 32] : src[d - 32];
    kpe[(size_t)s * DR + d] = (f16)rope_one(s, d, x, other);
}

// ---------------------------------------------------------------------------
// Flash attention, causal. fp32 VALU math, f16 inputs.
// grid (S/16, NH), 256 threads. Parallel softmax, O in registers.
// ---------------------------------------------------------------------------
#define BQ 16
#define BKA 32
#define KST 196              // fp32 row stride for Q/K (192 + 4, float4 aligned)
#define VST 132              // f16 row stride for V (128 + 4)

__global__ __launch_bounds__(256) void attn_fa_k(
    const f16* __restrict__ q, const f16* __restrict__ kv,
    const f16* __restrict__ kpe, f16* __restrict__ attn)
{
    __shared__ float Qs[BQ][KST];
    __shared__ float Ks[BKA][KST];
    __shared__ f16   Vs[BKA][VST];
    __shared__ float Ss[BQ][33];
    __shared__ float ms[BQ], ls[BQ], as_[BQ];

    const int tid = threadIdx.x;
    const int q0 = blockIdx.x * BQ;
    const int h = blockIdx.y;
    const float scale = 0.07216878364870323f;   // 1/sqrt(192)

    const int sr = tid >> 4, sg = tid & 15;     // score/softmax mapping
    const int orr = tid & 15, od = tid >> 4;    // O-update mapping

    // Q tile: f16 -> fp32 LDS
    for (int i = tid; i < BQ * 48; i += 256) {
        int r = i / 48, c4 = i % 48;
        half4 hv = *(const half4*)&q[(size_t)(q0 + r) * QB_N + h * HD_QK + c4 * 4];
        Qs[r][c4 * 4 + 0] = (float)hv[0];
        Qs[r][c4 * 4 + 1] = (float)hv[1];
        Qs[r][c4 * 4 + 2] = (float)hv[2];
        Qs[r][c4 * 4 + 3] = (float)hv[3];
    }
    if (tid < BQ) { ms[tid] = -1e30f; ls[tid] = 0.f; }
    float o[2][4] = {};
    __syncthreads();

    const int ntiles = (q0 + BQ + BKA - 1) / BKA;
    for (int kt = 0; kt < ntiles; ++kt) {
        const int k0 = kt * BKA;
        // stage K (k_nope ++ k_pe), fp32
        for (int i = tid; i < BKA * 48; i += 256) {
            int r = i / 48, c4 = i % 48;
            half4 hv;
            if (c4 < 32)
                hv = *(const half4*)&kv[(size_t)(k0 + r) * KVB_N + h * (DN + DV) + c4 * 4];
            else
                hv = *(const half4*)&kpe[(size_t)(k0 + r) * DR + (c4 - 32) * 4];
            Ks[r][c4 * 4 + 0] = (float)hv[0];
            Ks[r][c4 * 4 + 1] = (float)hv[1];
            Ks[r][c4 * 4 + 2] = (float)hv[2];
            Ks[r][c4 * 4 + 3] = (float)hv[3];
        }
        // stage V, keep f16
        for (int i = tid; i < BKA * 32; i += 256) {
            int r = i / 32, c4 = i % 32;
            half4 hv = *(const half4*)&kv[(size_t)(k0 + r) * KVB_N + h * (DN + DV) + DN + c4 * 4];
            *(half4*)&Vs[r][c4 * 4] = hv;
        }
        __syncthreads();

        // scores (2 cols/thread) + parallel online softmax
        float s0 = 0.f, s1 = 0.f;
        {
            const float4* qp = (const float4*)&Qs[sr][0];
            const float4* ka = (const float4*)&Ks[sg][0];
            const float4* kb = (const float4*)&Ks[sg + 16][0];
            #pragma unroll 8
            for (int d4 = 0; d4 < 48; ++d4) {
                float4 qv = qp[d4], va = ka[d4], vb = kb[d4];
                s0 += qv.x * va.x + qv.y * va.y + qv.z * va.z + qv.w * va.w;
                s1 += qv.x * vb.x + qv.y * vb.y + qv.z * vb.z + qv.w * vb.w;
            }
        }
        s0 = (k0 + sg      <= q0 + sr) ? s0 * scale : -1e30f;
        s1 = (k0 + sg + 16 <= q0 + sr) ? s1 * scale : -1e30f;
        float mx = fmaxf(s0, s1);
        mx = fmaxf(mx, __shfl_xor(mx, 1));
        mx = fmaxf(mx, __shfl_xor(mx, 2));
        mx = fmaxf(mx, __shfl_xor(mx, 4));
        mx = fmaxf(mx, __shfl_xor(mx, 8));
        float mold = ms[sr];
        float mnew = fmaxf(mold, mx);
        float p0 = __expf(s0 - mnew), p1 = __expf(s1 - mnew);
        float lsum = p0 + p1;
        lsum += __shfl_xor(lsum, 1);
        lsum += __shfl_xor(lsum, 2);
        lsum += __shfl_xor(lsum, 4);
        lsum += __shfl_xor(lsum, 8);
        Ss[sr][sg] = p0;
        Ss[sr][sg + 16] = p1;
        if (sg == 0) {
            float alpha = __expf(mold - mnew);
            as_[sr] = alpha;
            ms[sr] = mnew;
            ls[sr] = ls[sr] * alpha + lsum;
        }
        __syncthreads();

        // O update: row orr, d4 groups od and od+16 (V reads are broadcasts)
        {
            float a = as_[orr];
            #pragma unroll
            for (int p = 0; p < 2; ++p) {
                int d4 = od + p * 16;
                o[p][0] *= a; o[p][1] *= a; o[p][2] *= a; o[p][3] *= a;
                for (int c = 0; c < BKA; ++c) {
                    float pw = Ss[orr][c];
                    half4 vv = *(const half4*)&Vs[c][d4 * 4];
                    o[p][0] += pw * (float)vv[0];
                    o[p][1] += pw * (float)vv[1];
                    o[p][2] += pw * (float)vv[2];
                    o[p][3] += pw * (float)vv[3];
                }
            }
        }
        __syncthreads();
    }

    const float inv = 1.f / ls[orr];
    #pragma unroll
    for (int p = 0; p < 2; ++p) {
        int d4 = od + p * 16;
        #pragma unroll
        for (int u = 0; u < 4; ++u)
            attn[(size_t)(q0 + orr) * (NH * DV) + h * DV + d4 * 4 + u] =
                (f16)(o[p][u] * inv);
    }
}

// ---------------------------------------------------------------------------
// Launch
// ---------------------------------------------------------------------------
extern "C" void kernel_launch(void* const* d_in, const int* in_sizes, int n_in,
                              void* d_out, int out_size, void* d_ws, size_t ws_size,
                              hipStream_t stream)
{
    const float* hidden   = (const float*)d_in[0];
    const float* w_kv_a   = (const float*)d_in[1];
    const float* q_gamma  = (const float*)d_in[2];
    const float* w_qb     = (const float*)d_in[3];
    const float* kv_gamma = (const float*)d_in[4];
    const float* w_kvb    = (const float*)d_in[5];
    const float* w_o      = (const float*)d_in[6];
    float* out = (float*)d_out;

    // Workspace layout:
    //   hid_h   [2048][2048] f16
    //   wkva_t  [2176][2048] f16
    //   wqb_t   [3072][1536] f16
    //   wkvb_t  [4096][512]  f16
    //   wo_t    [2048][2048] f16
    //   fused   [2048][2176] f32
    //   q_n     [2048][1536] f16
    //   qbuf    [2048][3072] f16
    //   kv_n    [2048][512]  f16
    //   kvbuf   [2048][4096] f16
    //   kpe     [2048][64]   f16
    //   attnb   [2048][2048] f16
    char* p = (char*)d_ws;
    f16* hid_h   = (f16*)p;  p += (size_t)2048 * 2048 * 2;
    f16* wkva_t  = (f16*)p;  p += (size_t)2176 * 2048 * 2;
    f16* wqb_t   = (f16*)p;  p += (size_t)3072 * 1536 * 2;
    f16* wkvb_t  = (f16*)p;  p += (size_t)4096 * 512 * 2;
    f16* wo_t    = (f16*)p;  p += (size_t)2048 * 2048 * 2;
    float* fused = (float*)p; p += (size_t)2048 * FPAD * 4;
    f16* q_n     = (f16*)p;  p += (size_t)2048 * QL * 2;
    f16* qbuf    = (f16*)p;  p += (size_t)2048 * QB_N * 2;
    f16* kv_n    = (f16*)p;  p += (size_t)2048 * KL * 2;
    f16* kvbuf   = (f16*)p;  p += (size_t)2048 * KVB_N * 2;
    f16* kpe     = (f16*)p;  p += (size_t)2048 * DR * 2;
    f16* attnb   = (f16*)p;  p += (size_t)2048 * 2048 * 2;

    dim3 blk(256);

    // precision conversions (one-shot per launch)
    cvt_f16_k<<<(2048 * 2048 / 4 + 255) / 256, blk, 0, stream>>>(hidden, hid_h, 2048 * 2048 / 4);
    tconv_k<<<dim3(2176 / 32, 2048 / 32), blk, 0, stream>>>(w_kv_a, wkva_t, 2048, FUSED_N);
    tconv_k<<<dim3(3072 / 32, 1536 / 32), blk, 0, stream>>>(w_qb,   wqb_t,  1536, QB_N);
    tconv_k<<<dim3(4096 / 32,  512 / 32), blk, 0, stream>>>(w_kvb,  wkvb_t,  512, KVB_N);
    tconv_k<<<dim3(2048 / 32, 2048 / 32), blk, 0, stream>>>(w_o,    wo_t,   2048, 2048);

    // 1. fused = hidden @ w_kv_a   (M=2048, N=2176(pad), K=2048) -> fp32
    gemm_mfma<0><<<dim3(FPAD / 128, 2048 / 128), blk, 0, stream>>>(
        hid_h, wkva_t, fused, 2048, FPAD, 2048);

    // 2. RMSNorms -> f16
    rmsnorm_k<<<2048, blk, 0, stream>>>(fused, FPAD, QL, q_gamma, q_n);
    rmsnorm_k<<<2048, blk, 0, stream>>>(fused + QL, FPAD, KL, kv_gamma, kv_n);

    // 3. q = q_n @ w_qb            (2048 x 3072 x 1536) -> f16
    gemm_mfma<1><<<dim3(QB_N / 128, 2048 / 128), blk, 0, stream>>>(
        q_n, wqb_t, qbuf, 2048, QB_N, QL);

    // 4. kv = kv_n @ w_kvb         (2048 x 4096 x 512) -> f16
    gemm_mfma<1><<<dim3(KVB_N / 128, 2048 / 128), blk, 0, stream>>>(
        kv_n, wkvb_t, kvbuf, 2048, KVB_N, KL);

    // 5. RoPE
    rope_q_k<<<dim3(2048, NH), dim3(64), 0, stream>>>(qbuf);
    rope_kpe_k<<<2048, dim3(64), 0, stream>>>(fused, kpe);

    // 6. attention
    attn_fa_k<<<dim3(2048 / BQ, NH), blk, 0, stream>>>(qbuf, kvbuf, kpe, attnb);

    // 7. out = attn @ w_o          (2048 x 2048 x 2048) -> fp32
    gemm_mfma<0><<<dim3(2048 / 128, 2048 / 128), blk, 0, stream>>>(
        attnb, wo_t, out, 2048, 2048, 2048);
}

// Round 4
// 476.725 us; speedup vs baseline: 8.2806x; 2.9982x over previous
//
#include <hip/hip_runtime.h>
#include <math.h>

#define S_LEN 2048
#define NH 16
#define DN 128
#define DR 64
#define DV 128
#define QL 1536
#define KL 512
#define FUSED_N 2112
#define FPAD 2176            // fused padded to 17*128 for uniform GEMM tiles
#define QB_N 3072
#define KVB_N 4096
#define HD_QK 192
#define EPS_RMS 1e-6f

typedef _Float16 f16;
typedef _Float16 half8 __attribute__((ext_vector_type(8)));
typedef _Float16 half4 __attribute__((ext_vector_type(4)));
typedef float floatx4 __attribute__((ext_vector_type(4)));

// ---------------------------------------------------------------------------
// fp32 -> f16 elementwise (4/thread)
// ---------------------------------------------------------------------------
__global__ __launch_bounds__(256) void cvt_f16_k(const float* __restrict__ in,
                                                 f16* __restrict__ out, int n4)
{
    int i = blockIdx.x * 256 + threadIdx.x;
    if (i < n4) {
        float4 v = ((const float4*)in)[i];
        half4 h;
        h[0] = (f16)v.x; h[1] = (f16)v.y; h[2] = (f16)v.z; h[3] = (f16)v.w;
        ((half4*)out)[i] = h;
    }
}

// ---------------------------------------------------------------------------
// fp32 [K][N] -> f16 B^T [Npad][K]; rows n>=N zero-filled.
// ---------------------------------------------------------------------------
__global__ __launch_bounds__(256) void tconv_k(const float* __restrict__ in,
                                               f16* __restrict__ out,
                                               int K, int N)
{
    __shared__ float t[32][33];
    const int k0 = blockIdx.y * 32, n0 = blockIdx.x * 32;
    const int c = threadIdx.x & 31, r8 = threadIdx.x >> 5;
    #pragma unroll
    for (int i = 0; i < 4; ++i) {
        int r = r8 + i * 8;
        int gc = n0 + c;
        t[r][c] = (gc < N) ? in[(size_t)(k0 + r) * N + gc] : 0.f;
    }
    __syncthreads();
    #pragma unroll
    for (int i = 0; i < 4; ++i) {
        int r = r8 + i * 8;     // local n
        out[(size_t)(n0 + r) * K + k0 + c] = (f16)t[c][r];
    }
}

// ---------------------------------------------------------------------------
// f16 MFMA GEMM: C[M,N] = A[M,K] @ Bt[N,K]^T.  128x128 tile, BK=64.
// ---------------------------------------------------------------------------
__device__ __forceinline__ void async16(const f16* gp, f16* lp)
{
    __builtin_amdgcn_global_load_lds(
        (const __attribute__((address_space(1))) void*)gp,
        (__attribute__((address_space(3))) void*)lp, 16, 0, 0);
}

template <int OUT_F16>
__global__ __launch_bounds__(256) void gemm_mfma(
    const f16* __restrict__ A,   // [M][K]
    const f16* __restrict__ Bt,  // [N][K]
    void* __restrict__ Cv, int M, int N, int K)
{
    __shared__ f16 As[128 * 64];
    __shared__ f16 Bs[128 * 64];

    const int tid = threadIdx.x;
    const int wv = tid >> 6, lane = tid & 63;
    const int quad = lane >> 4, l15 = lane & 15;
    const int wr = wv >> 1, wc = wv & 1;
    const int bm = blockIdx.y * 128, bn = blockIdx.x * 128;
    const int srow = lane >> 3;      // 0..7
    const int sc = lane & 7;         // slot chunk 0..7

    floatx4 acc[4][4] = {};

    for (int k0 = 0; k0 < K; k0 += 64) {
        #pragma unroll
        for (int t = 0; t < 4; ++t) {
            int rl = wv * 32 + t * 8 + srow;     // local row 0..127
            int ch = sc ^ (rl & 7);              // data chunk for this slot
            async16(A  + (size_t)(bm + rl) * K + k0 + ch * 8,
                    &As[(wv * 32 + t * 8) * 64]);
            async16(Bt + (size_t)(bn + rl) * K + k0 + ch * 8,
                    &Bs[(wv * 32 + t * 8) * 64]);
        }
        __syncthreads();

        #pragma unroll
        for (int ks = 0; ks < 2; ++ks) {
            half8 av[4], bv[4];
            #pragma unroll
            for (int i = 0; i < 4; ++i) {
                int m = wr * 64 + i * 16 + l15;
                av[i] = *(const half8*)&As[m * 64 + ((ks * 4 + quad) ^ (m & 7)) * 8];
            }
            #pragma unroll
            for (int j = 0; j < 4; ++j) {
                int n = wc * 64 + j * 16 + l15;
                bv[j] = *(const half8*)&Bs[n * 64 + ((ks * 4 + quad) ^ (n & 7)) * 8];
            }
            #pragma unroll
            for (int i = 0; i < 4; ++i)
                #pragma unroll
                for (int j = 0; j < 4; ++j)
                    acc[i][j] = __builtin_amdgcn_mfma_f32_16x16x32_f16(
                        av[i], bv[j], acc[i][j], 0, 0, 0);
        }
        __syncthreads();
    }

    #pragma unroll
    for (int i = 0; i < 4; ++i) {
        int rbase = bm + wr * 64 + i * 16 + quad * 4;
        #pragma unroll
        for (int j = 0; j < 4; ++j) {
            int cidx = bn + wc * 64 + j * 16 + l15;
            #pragma unroll
            for (int rr = 0; rr < 4; ++rr) {
                if (OUT_F16)
                    ((f16*)Cv)[(size_t)(rbase + rr) * N + cidx] = (f16)acc[i][j][rr];
                else
                    ((float*)Cv)[(size_t)(rbase + rr) * N + cidx] = acc[i][j][rr];
            }
        }
    }
}

// ---------------------------------------------------------------------------
// RMSNorm: fp32 strided in -> f16 compact out
// ---------------------------------------------------------------------------
__global__ __launch_bounds__(256) void rmsnorm_k(
    const float* __restrict__ in, int stride, int ncols,
    const float* __restrict__ gamma, f16* __restrict__ out)
{
    const int row = blockIdx.x;
    const float* x = in + (size_t)row * stride;

    float ss = 0.f;
    for (int c = threadIdx.x; c < ncols; c += 256) {
        float v = x[c];
        ss += v * v;
    }
    #pragma unroll
    for (int off = 32; off > 0; off >>= 1) ss += __shfl_down(ss, off);

    __shared__ float warp_s[4];
    __shared__ float scale_s;
    const int wid = threadIdx.x >> 6;
    if ((threadIdx.x & 63) == 0) warp_s[wid] = ss;
    __syncthreads();
    if (threadIdx.x == 0) {
        float t = warp_s[0] + warp_s[1] + warp_s[2] + warp_s[3];
        scale_s = rsqrtf(t / (float)ncols + EPS_RMS);
    }
    __syncthreads();
    const float sc = scale_s;
    for (int c = threadIdx.x; c < ncols; c += 256)
        out[(size_t)row * ncols + c] = (f16)(x[c] * gamma[c] * sc);
}

// ---------------------------------------------------------------------------
// RoPE
// ---------------------------------------------------------------------------
__device__ __forceinline__ float rope_one(int s, int d, float x, float other)
{
    const int j = d & 31;
    const float invf = expf(-0.28782313662425572f * (float)j); // 10000^(-j/32)
    const float ang = (float)s * invf;
    float sn, cs;
    sincosf(ang, &sn, &cs);
    float rot = (d < 32) ? -other : other;
    return x * cs + rot * sn;
}

// grid (S, 4), block 256: each wave rotates one head's q_pe
__global__ __launch_bounds__(256) void rope_q_k(f16* __restrict__ q)
{
    const int s = blockIdx.x;
    const int h = blockIdx.y * 4 + (threadIdx.x >> 6);
    const int d = threadIdx.x & 63;
    f16* base = q + (size_t)s * QB_N + h * HD_QK + DN;
    float x = (float)base[d];
    float other = (float)((d < 32) ? base[d + 32] : base[d - 32]);
    base[d] = (f16)rope_one(s, d, x, other);
}

__global__ void rope_kpe_k(const float* __restrict__ fused, f16* __restrict__ kpe)
{
    const int s = blockIdx.x, d = threadIdx.x;
    const float* src = fused + (size_t)s * FPAD + (QL + KL);
    float x = src[d];
    float other = (d < 32) ? src[d + 32] : src[d - 32];
    kpe[(size_t)s * DR + d] = (f16)rope_one(s, d, x, other);
}

// ---------------------------------------------------------------------------
// kfull[h][s][192] = concat(kvbuf[s][h*256 + 0..127], kpe[s][0..63])
// flat over half8 chunks: 16*2048*24
// ---------------------------------------------------------------------------
__global__ __launch_bounds__(256) void kfull_k(const f16* __restrict__ kv,
                                               const f16* __restrict__ kpe,
                                               f16* __restrict__ kfull)
{
    int n = blockIdx.x * 256 + threadIdx.x;   // < 16*2048*24
    int c8 = n % 24;
    int s = (n / 24) & 2047;
    int h = n / (24 * 2048);
    half8 v;
    if (c8 < 16)
        v = *(const half8*)&kv[(size_t)s * KVB_N + h * 256 + c8 * 8];
    else
        v = *(const half8*)&kpe[(size_t)s * DR + (c8 - 16) * 8];
    *(half8*)&kfull[((size_t)h * S_LEN + s) * HD_QK + c8 * 8] = v;
}

// ---------------------------------------------------------------------------
// vt[h][d][s] = kvbuf[s][h*256 + 128 + d]   (V transpose, 32x32 tiles)
// grid (S/32, 128/32, NH)
// ---------------------------------------------------------------------------
__global__ __launch_bounds__(256) void vt_k(const f16* __restrict__ kv,
                                            f16* __restrict__ vt)
{
    __shared__ f16 t[32][33];
    const int s0 = blockIdx.x * 32, d0 = blockIdx.y * 32, h = blockIdx.z;
    const int tid = threadIdx.x;
    {
        const int c = tid & 31, rb = tid >> 5;
        #pragma unroll
        for (int i = 0; i < 4; ++i) {
            int r = rb + i * 8;  // s offset
            t[r][c] = kv[(size_t)(s0 + r) * KVB_N + h * 256 + 128 + d0 + c];
        }
    }
    __syncthreads();
    {
        const int d = tid >> 3, s4 = tid & 7;
        half4 v;
        v[0] = t[s4 * 4 + 0][d];
        v[1] = t[s4 * 4 + 1][d];
        v[2] = t[s4 * 4 + 2][d];
        v[3] = t[s4 * 4 + 3][d];
        *(half4*)&vt[((size_t)h * DV + d0 + d) * S_LEN + s0 + s4 * 4] = v;
    }
}

// ---------------------------------------------------------------------------
// MFMA flash attention (causal). Block = 64 Q-rows x 1 head, 4 waves x 16 rows.
// K-tile = 32 keys. QK^T and PV on mfma_f32_16x16x32_f16; online softmax on
// C-layout frags; P transforms C->A layout via wave-private LDS.
// LDS (f16 units):
//   [0,12800)  Q stage 64x200  --> after frag preload, reused as:
//      Ks [0,6400)   32x200     VTs [6400,11520) 128x40
//   [12800,15360) P: 4 waves x 16x40
// ---------------------------------------------------------------------------
__global__ __launch_bounds__(256) void attn_mfma_k(
    const f16* __restrict__ q,      // [S][3072]
    const f16* __restrict__ kfull,  // [NH][S][192]
    const f16* __restrict__ vt,     // [NH][128][S]
    f16* __restrict__ attn)         // [S][2048]
{
    __shared__ f16 sm[15360];
    f16* Qs  = sm;            // stride 200
    f16* Ks  = sm;            // stride 200 (alias)
    f16* VTs = sm + 6400;     // stride 40
    f16* Ps  = sm + 12800;    // per wave 16x40

    const int tid = threadIdx.x;
    const int w = tid >> 6, lane = tid & 63;
    const int quad = lane >> 4, l15 = lane & 15;
    const int q0 = blockIdx.x * 64;
    const int h = blockIdx.y;
    const float scale = 0.07216878364870323f;   // 1/sqrt(192)

    // stage Q (64 x 192) -> Qs
    for (int i = tid; i < 64 * 24; i += 256) {
        int r = i / 24, c8 = i % 24;
        *(half8*)&Qs[r * 200 + c8 * 8] =
            *(const half8*)&q[(size_t)(q0 + r) * QB_N + h * HD_QK + c8 * 8];
    }
    __syncthreads();
    half8 qf[6];
    #pragma unroll
    for (int kd = 0; kd < 6; ++kd)
        qf[kd] = *(const half8*)&Qs[(w * 16 + l15) * 200 + kd * 32 + quad * 8];
    __syncthreads();   // Qs dead; Ks/VTs may now overwrite

    floatx4 o[8] = {};
    float m_i[4], l_i[4];
    #pragma unroll
    for (int r = 0; r < 4; ++r) { m_i[r] = -1e30f; l_i[r] = 0.f; }

    const int qrow_min = q0 + w * 16;
    const int ntiles = q0 / 32 + 2;
    f16* Pw = Ps + w * 640;

    for (int kt = 0; kt < ntiles; ++kt) {
        const int k0 = kt * 32;
        // stage K tile (32 x 192)
        for (int i = tid; i < 32 * 24; i += 256) {
            int r = i / 24, c8 = i % 24;
            *(half8*)&Ks[r * 200 + c8 * 8] =
                *(const half8*)&kfull[((size_t)h * S_LEN + k0 + r) * HD_QK + c8 * 8];
        }
        // stage V^T tile (128 x 32)
        for (int i = tid; i < 128 * 4; i += 256) {
            int r = i / 4, c8 = i % 4;
            *(half8*)&VTs[r * 40 + c8 * 8] =
                *(const half8*)&vt[((size_t)h * DV + r) * S_LEN + k0 + c8 * 8];
        }
        __syncthreads();

        // QK^T: S[16 x 32]
        floatx4 s0 = {}, s1 = {};
        #pragma unroll
        for (int kd = 0; kd < 6; ++kd) {
            half8 b0 = *(const half8*)&Ks[l15 * 200 + kd * 32 + quad * 8];
            half8 b1 = *(const half8*)&Ks[(16 + l15) * 200 + kd * 32 + quad * 8];
            s0 = __builtin_amdgcn_mfma_f32_16x16x32_f16(qf[kd], b0, s0, 0, 0, 0);
            s1 = __builtin_amdgcn_mfma_f32_16x16x32_f16(qf[kd], b1, s1, 0, 0, 0);
        }

        // mask + scale + tile row-max
        const bool nm = (k0 + 31 > qrow_min);
        float mt[4];
        #pragma unroll
        for (int r = 0; r < 4; ++r) {
            float v0 = s0[r] * scale, v1 = s1[r] * scale;
            if (nm) {
                int row = qrow_min + quad * 4 + r;
                if (k0 + l15 > row)      v0 = -1e30f;
                if (k0 + 16 + l15 > row) v1 = -1e30f;
            }
            s0[r] = v0; s1[r] = v1;
            mt[r] = fmaxf(v0, v1);
        }
        #pragma unroll
        for (int r = 0; r < 4; ++r) {
            mt[r] = fmaxf(mt[r], __shfl_xor(mt[r], 1));
            mt[r] = fmaxf(mt[r], __shfl_xor(mt[r], 2));
            mt[r] = fmaxf(mt[r], __shfl_xor(mt[r], 4));
            mt[r] = fmaxf(mt[r], __shfl_xor(mt[r], 8));
        }
        float alpha[4], ps[4];
        #pragma unroll
        for (int r = 0; r < 4; ++r) {
            float mn = fmaxf(m_i[r], mt[r]);
            alpha[r] = __expf(m_i[r] - mn);
            m_i[r] = mn;
            float p0 = __expf(s0[r] - mn);
            float p1 = __expf(s1[r] - mn);
            s0[r] = p0; s1[r] = p1;
            ps[r] = p0 + p1;
        }
        #pragma unroll
        for (int r = 0; r < 4; ++r) {
            ps[r] += __shfl_xor(ps[r], 1);
            ps[r] += __shfl_xor(ps[r], 2);
            ps[r] += __shfl_xor(ps[r], 4);
            ps[r] += __shfl_xor(ps[r], 8);
            l_i[r] = l_i[r] * alpha[r] + ps[r];
        }

        // P: C-layout -> wave-private LDS (f16)
        #pragma unroll
        for (int r = 0; r < 4; ++r) {
            Pw[(quad * 4 + r) * 40 + l15]      = (f16)s0[r];
            Pw[(quad * 4 + r) * 40 + 16 + l15] = (f16)s1[r];
        }

        // rescale O
        #pragma unroll
        for (int nb = 0; nb < 8; ++nb)
            #pragma unroll
            for (int r = 0; r < 4; ++r) o[nb][r] *= alpha[r];

        // PV: A-layout P read back, 8 dv-blocks
        half8 pa = *(const half8*)&Pw[l15 * 40 + quad * 8];
        #pragma unroll
        for (int nb = 0; nb < 8; ++nb) {
            half8 vb = *(const half8*)&VTs[(nb * 16 + l15) * 40 + quad * 8];
            o[nb] = __builtin_amdgcn_mfma_f32_16x16x32_f16(pa, vb, o[nb], 0, 0, 0);
        }
        __syncthreads();
    }

    float inv[4];
    #pragma unroll
    for (int r = 0; r < 4; ++r) inv[r] = 1.f / l_i[r];
    #pragma unroll
    for (int nb = 0; nb < 8; ++nb) {
        #pragma unroll
        for (int r = 0; r < 4; ++r) {
            int row = q0 + w * 16 + quad * 4 + r;
            attn[(size_t)row * (NH * DV) + h * DV + nb * 16 + l15] =
                (f16)(o[nb][r] * inv[r]);
        }
    }
}

// ---------------------------------------------------------------------------
// Launch
// ---------------------------------------------------------------------------
extern "C" void kernel_launch(void* const* d_in, const int* in_sizes, int n_in,
                              void* d_out, int out_size, void* d_ws, size_t ws_size,
                              hipStream_t stream)
{
    const float* hidden   = (const float*)d_in[0];
    const float* w_kv_a   = (const float*)d_in[1];
    const float* q_gamma  = (const float*)d_in[2];
    const float* w_qb     = (const float*)d_in[3];
    const float* kv_gamma = (const float*)d_in[4];
    const float* w_kvb    = (const float*)d_in[5];
    const float* w_o      = (const float*)d_in[6];
    float* out = (float*)d_out;

    char* p = (char*)d_ws;
    f16* hid_h   = (f16*)p;  p += (size_t)2048 * 2048 * 2;
    f16* wkva_t  = (f16*)p;  p += (size_t)2176 * 2048 * 2;
    f16* wqb_t   = (f16*)p;  p += (size_t)3072 * 1536 * 2;
    f16* wkvb_t  = (f16*)p;  p += (size_t)4096 * 512 * 2;
    f16* wo_t    = (f16*)p;  p += (size_t)2048 * 2048 * 2;
    float* fused = (float*)p; p += (size_t)2048 * FPAD * 4;
    f16* q_n     = (f16*)p;  p += (size_t)2048 * QL * 2;
    f16* qbuf    = (f16*)p;  p += (size_t)2048 * QB_N * 2;
    f16* kv_n    = (f16*)p;  p += (size_t)2048 * KL * 2;
    f16* kvbuf   = (f16*)p;  p += (size_t)2048 * KVB_N * 2;
    f16* kpe     = (f16*)p;  p += (size_t)2048 * DR * 2;
    f16* attnb   = (f16*)p;  p += (size_t)2048 * 2048 * 2;

    // aliases onto dead regions (no extra ws):
    //   kfull [16][2048][192] f16 (12.6 MB) <- hid_h+wkva_t (17.3 MB, dead after gemm1)
    //   vt    [16][128][2048] f16 ( 8.4 MB) <- fused (17.8 MB, dead after rmsnorm/rope)
    f16* kfull = hid_h;
    f16* vt    = (f16*)fused;

    dim3 blk(256);

    cvt_f16_k<<<(2048 * 2048 / 4 + 255) / 256, blk, 0, stream>>>(hidden, hid_h, 2048 * 2048 / 4);
    tconv_k<<<dim3(2176 / 32, 2048 / 32), blk, 0, stream>>>(w_kv_a, wkva_t, 2048, FUSED_N);
    tconv_k<<<dim3(3072 / 32, 1536 / 32), blk, 0, stream>>>(w_qb,   wqb_t,  1536, QB_N);
    tconv_k<<<dim3(4096 / 32,  512 / 32), blk, 0, stream>>>(w_kvb,  wkvb_t,  512, KVB_N);
    tconv_k<<<dim3(2048 / 32, 2048 / 32), blk, 0, stream>>>(w_o,    wo_t,   2048, 2048);

    gemm_mfma<0><<<dim3(FPAD / 128, 2048 / 128), blk, 0, stream>>>(
        hid_h, wkva_t, fused, 2048, FPAD, 2048);

    rmsnorm_k<<<2048, blk, 0, stream>>>(fused, FPAD, QL, q_gamma, q_n);
    rmsnorm_k<<<2048, blk, 0, stream>>>(fused + QL, FPAD, KL, kv_gamma, kv_n);

    gemm_mfma<1><<<dim3(QB_N / 128, 2048 / 128), blk, 0, stream>>>(
        q_n, wqb_t, qbuf, 2048, QB_N, QL);
    gemm_mfma<1><<<dim3(KVB_N / 128, 2048 / 128), blk, 0, stream>>>(
        kv_n, wkvb_t, kvbuf, 2048, KVB_N, KL);

    rope_q_k<<<dim3(2048, 4), blk, 0, stream>>>(qbuf);
    rope_kpe_k<<<2048, dim3(64), 0, stream>>>(fused, kpe);

    // prep attention operands (after fused/hid_h/wkva_t are dead)
    kfull_k<<<16 * 2048 * 24 / 256, blk, 0, stream>>>(kvbuf, kpe, kfull);
    vt_k<<<dim3(2048 / 32, 128 / 32, NH), blk, 0, stream>>>(kvbuf, vt);

    attn_mfma_k<<<dim3(2048 / 64, NH), blk, 0, stream>>>(qbuf, kfull, vt, attnb);

    gemm_mfma<0><<<dim3(2048 / 128, 2048 / 128), blk, 0, stream>>>(
        attnb, wo_t, out, 2048, 2048, 2048);
}

// Round 5
// 402.779 us; speedup vs baseline: 9.8008x; 1.1836x over previous
//
#include <hip/hip_runtime.h>
#include <math.h>

#define S_LEN 2048
#define NH 16
#define DN 128
#define DR 64
#define DV 128
#define QL 1536
#define KL 512
#define FUSED_N 2112
#define FPAD 2176            // fused padded to 17*128 for uniform GEMM tiles
#define QB_N 3072
#define KVB_N 4096
#define HD_QK 192
#define EPS_RMS 1e-6f

typedef _Float16 f16;
typedef _Float16 half8 __attribute__((ext_vector_type(8)));
typedef _Float16 half4 __attribute__((ext_vector_type(4)));
typedef float floatx4 __attribute__((ext_vector_type(4)));

// ---------------------------------------------------------------------------
// fp32 -> f16 elementwise (4/thread)
// ---------------------------------------------------------------------------
__global__ __launch_bounds__(256) void cvt_f16_k(const float* __restrict__ in,
                                                 f16* __restrict__ out, int n4)
{
    int i = blockIdx.x * 256 + threadIdx.x;
    if (i < n4) {
        float4 v = ((const float4*)in)[i];
        half4 h;
        h[0] = (f16)v.x; h[1] = (f16)v.y; h[2] = (f16)v.z; h[3] = (f16)v.w;
        ((half4*)out)[i] = h;
    }
}

// ---------------------------------------------------------------------------
// fp32 [K][N] -> f16 B^T [Npad][K]; rows n>=N zero-filled.
// ---------------------------------------------------------------------------
__global__ __launch_bounds__(256) void tconv_k(const float* __restrict__ in,
                                               f16* __restrict__ out,
                                               int K, int N)
{
    __shared__ float t[32][33];
    const int k0 = blockIdx.y * 32, n0 = blockIdx.x * 32;
    const int c = threadIdx.x & 31, r8 = threadIdx.x >> 5;
    #pragma unroll
    for (int i = 0; i < 4; ++i) {
        int r = r8 + i * 8;
        int gc = n0 + c;
        t[r][c] = (gc < N) ? in[(size_t)(k0 + r) * N + gc] : 0.f;
    }
    __syncthreads();
    #pragma unroll
    for (int i = 0; i < 4; ++i) {
        int r = r8 + i * 8;     // local n
        out[(size_t)(n0 + r) * K + k0 + c] = (f16)t[c][r];
    }
}

// ---------------------------------------------------------------------------
// f16 MFMA GEMM: C[M,N] = A[M,K] @ Bt[N,K]^T.  128x128 tile, BK=64.
// ---------------------------------------------------------------------------
__device__ __forceinline__ void async16(const f16* gp, f16* lp)
{
    __builtin_amdgcn_global_load_lds(
        (const __attribute__((address_space(1))) void*)gp,
        (__attribute__((address_space(3))) void*)lp, 16, 0, 0);
}

template <int OUT_F16>
__global__ __launch_bounds__(256) void gemm_mfma(
    const f16* __restrict__ A,   // [M][K]
    const f16* __restrict__ Bt,  // [N][K]
    void* __restrict__ Cv, int M, int N, int K)
{
    __shared__ f16 As[128 * 64];
    __shared__ f16 Bs[128 * 64];

    const int tid = threadIdx.x;
    const int wv = tid >> 6, lane = tid & 63;
    const int quad = lane >> 4, l15 = lane & 15;
    const int wr = wv >> 1, wc = wv & 1;
    const int bm = blockIdx.y * 128, bn = blockIdx.x * 128;
    const int srow = lane >> 3;      // 0..7
    const int sc = lane & 7;         // slot chunk 0..7

    floatx4 acc[4][4] = {};

    for (int k0 = 0; k0 < K; k0 += 64) {
        #pragma unroll
        for (int t = 0; t < 4; ++t) {
            int rl = wv * 32 + t * 8 + srow;     // local row 0..127
            int ch = sc ^ (rl & 7);              // data chunk for this slot
            async16(A  + (size_t)(bm + rl) * K + k0 + ch * 8,
                    &As[(wv * 32 + t * 8) * 64]);
            async16(Bt + (size_t)(bn + rl) * K + k0 + ch * 8,
                    &Bs[(wv * 32 + t * 8) * 64]);
        }
        __syncthreads();

        #pragma unroll
        for (int ks = 0; ks < 2; ++ks) {
            half8 av[4], bv[4];
            #pragma unroll
            for (int i = 0; i < 4; ++i) {
                int m = wr * 64 + i * 16 + l15;
                av[i] = *(const half8*)&As[m * 64 + ((ks * 4 + quad) ^ (m & 7)) * 8];
            }
            #pragma unroll
            for (int j = 0; j < 4; ++j) {
                int n = wc * 64 + j * 16 + l15;
                bv[j] = *(const half8*)&Bs[n * 64 + ((ks * 4 + quad) ^ (n & 7)) * 8];
            }
            #pragma unroll
            for (int i = 0; i < 4; ++i)
                #pragma unroll
                for (int j = 0; j < 4; ++j)
                    acc[i][j] = __builtin_amdgcn_mfma_f32_16x16x32_f16(
                        av[i], bv[j], acc[i][j], 0, 0, 0);
        }
        __syncthreads();
    }

    #pragma unroll
    for (int i = 0; i < 4; ++i) {
        int rbase = bm + wr * 64 + i * 16 + quad * 4;
        #pragma unroll
        for (int j = 0; j < 4; ++j) {
            int cidx = bn + wc * 64 + j * 16 + l15;
            #pragma unroll
            for (int rr = 0; rr < 4; ++rr) {
                if (OUT_F16)
                    ((f16*)Cv)[(size_t)(rbase + rr) * N + cidx] = (f16)acc[i][j][rr];
                else
                    ((float*)Cv)[(size_t)(rbase + rr) * N + cidx] = acc[i][j][rr];
            }
        }
    }
}

// ---------------------------------------------------------------------------
// RMSNorm: fp32 strided in -> f16 compact out
// ---------------------------------------------------------------------------
__global__ __launch_bounds__(256) void rmsnorm_k(
    const float* __restrict__ in, int stride, int ncols,
    const float* __restrict__ gamma, f16* __restrict__ out)
{
    const int row = blockIdx.x;
    const float* x = in + (size_t)row * stride;

    float ss = 0.f;
    for (int c = threadIdx.x; c < ncols; c += 256) {
        float v = x[c];
        ss += v * v;
    }
    #pragma unroll
    for (int off = 32; off > 0; off >>= 1) ss += __shfl_down(ss, off);

    __shared__ float warp_s[4];
    __shared__ float scale_s;
    const int wid = threadIdx.x >> 6;
    if ((threadIdx.x & 63) == 0) warp_s[wid] = ss;
    __syncthreads();
    if (threadIdx.x == 0) {
        float t = warp_s[0] + warp_s[1] + warp_s[2] + warp_s[3];
        scale_s = rsqrtf(t / (float)ncols + EPS_RMS);
    }
    __syncthreads();
    const float sc = scale_s;
    for (int c = threadIdx.x; c < ncols; c += 256)
        out[(size_t)row * ncols + c] = (f16)(x[c] * gamma[c] * sc);
}

// ---------------------------------------------------------------------------
// RoPE
// ---------------------------------------------------------------------------
__device__ __forceinline__ float rope_one(int s, int d, float x, float other)
{
    const int j = d & 31;
    const float invf = expf(-0.28782313662425572f * (float)j); // 10000^(-j/32)
    const float ang = (float)s * invf;
    float sn, cs;
    sincosf(ang, &sn, &cs);
    float rot = (d < 32) ? -other : other;
    return x * cs + rot * sn;
}

// grid (S, 4), block 256: each wave rotates one head's q_pe
__global__ __launch_bounds__(256) void rope_q_k(f16* __restrict__ q)
{
    const int s = blockIdx.x;
    const int h = blockIdx.y * 4 + (threadIdx.x >> 6);
    const int d = threadIdx.x & 63;
    f16* base = q + (size_t)s * QB_N + h * HD_QK + DN;
    float x = (float)base[d];
    float other = (float)((d < 32) ? base[d + 32] : base[d - 32]);
    base[d] = (f16)rope_one(s, d, x, other);
}

__global__ void rope_kpe_k(const float* __restrict__ fused, f16* __restrict__ kpe)
{
    const int s = blockIdx.x, d = threadIdx.x;
    const float* src = fused + (size_t)s * FPAD + (QL + KL);
    float x = src[d];
    float other = (d < 32) ? src[d + 32] : src[d - 32];
    kpe[(size_t)s * DR + d] = (f16)rope_one(s, d, x, other);
}

// ---------------------------------------------------------------------------
// kfull[h][s][192] = concat(kvbuf[s][h*256 + 0..127], kpe[s][0..63])
// ---------------------------------------------------------------------------
__global__ __launch_bounds__(256) void kfull_k(const f16* __restrict__ kv,
                                               const f16* __restrict__ kpe,
                                               f16* __restrict__ kfull)
{
    int n = blockIdx.x * 256 + threadIdx.x;   // < 16*2048*24
    int c8 = n % 24;
    int s = (n / 24) & 2047;
    int h = n / (24 * 2048);
    half8 v;
    if (c8 < 16)
        v = *(const half8*)&kv[(size_t)s * KVB_N + h * 256 + c8 * 8];
    else
        v = *(const half8*)&kpe[(size_t)s * DR + (c8 - 16) * 8];
    *(half8*)&kfull[((size_t)h * S_LEN + s) * HD_QK + c8 * 8] = v;
}

// ---------------------------------------------------------------------------
// vt[h][d][s] = kvbuf[s][h*256 + 128 + d]   (V transpose, 32x32 tiles)
// ---------------------------------------------------------------------------
__global__ __launch_bounds__(256) void vt_k(const f16* __restrict__ kv,
                                            f16* __restrict__ vt)
{
    __shared__ f16 t[32][33];
    const int s0 = blockIdx.x * 32, d0 = blockIdx.y * 32, h = blockIdx.z;
    const int tid = threadIdx.x;
    {
        const int c = tid & 31, rb = tid >> 5;
        #pragma unroll
        for (int i = 0; i < 4; ++i) {
            int r = rb + i * 8;  // s offset
            t[r][c] = kv[(size_t)(s0 + r) * KVB_N + h * 256 + 128 + d0 + c];
        }
    }
    __syncthreads();
    {
        const int d = tid >> 3, s4 = tid & 7;
        half4 v;
        v[0] = t[s4 * 4 + 0][d];
        v[1] = t[s4 * 4 + 1][d];
        v[2] = t[s4 * 4 + 2][d];
        v[3] = t[s4 * 4 + 3][d];
        *(half4*)&vt[((size_t)h * DV + d0 + d) * S_LEN + s0 + s4 * 4] = v;
    }
}

// ---------------------------------------------------------------------------
// MFMA flash attention (causal), double-buffered async staging.
// Block = 64 Q-rows x 1 head (4 waves x 16 rows), K-tile = 32 keys.
// All staging via global_load_lds w16; chunk-XOR swizzle -> <=2-way LDS reads.
// Work-balance: qb = (y<8) ? x : 31-x  (pairs heavy+light on each CU).
//
// LDS map (f16 units, total 25088 = 50 KB):
//   Ks0 [0,6144)    32x192   buf0 K
//   V0  [6144,10240) 128x32  buf0 V^T
//   Q   [10240,22528) 64x192 staging; after frag preload becomes:
//     Ks1 [10240,16384), V1 [16384,20480)   (buf1)
//   P   [22528,25088)  4 waves x 16x40
// ---------------------------------------------------------------------------
__global__ __launch_bounds__(256) void attn_mfma_k(
    const f16* __restrict__ q,      // [S][3072]
    const f16* __restrict__ kfull,  // [NH][S][192]
    const f16* __restrict__ vt,     // [NH][128][S]
    f16* __restrict__ attn)         // [S][2048]
{
    __shared__ f16 sm[25088];

    const int tid = threadIdx.x;
    const int w = tid >> 6, lane = tid & 63;
    const int quad = lane >> 4, l15 = lane & 15;
    const int wbase = w * 64;
    const int h = blockIdx.y;
    const int qb = (blockIdx.y < 8) ? (int)blockIdx.x : 31 - (int)blockIdx.x;
    const int q0 = qb * 64;
    const float scale2 = 0.10411755f;   // (1/sqrt(192)) * log2(e)

    const f16* kf_h = kfull + (size_t)h * S_LEN * HD_QK;
    const f16* vt_h = vt + (size_t)h * DV * S_LEN;

    // staging slot decodes (k0-independent)
    int koff[3];
    #pragma unroll
    for (int j = 0; j < 3; ++j) {
        int sig = j * 256 + tid;
        int r = sig / 24, cs = sig - r * 24;
        int ch = (cs & 24) | ((cs & 7) ^ (r & 7));
        koff[j] = r * HD_QK + ch * 8;
    }
    int voff[2];
    #pragma unroll
    for (int j = 0; j < 2; ++j) {
        int sig = j * 256 + tid;
        int rv = sig >> 2, c = (sig & 3) ^ ((rv >> 1) & 3);
        voff[j] = rv * S_LEN + c * 8;
    }

    // stage Q (64x192) -> sm+10240, and K/V tile0 -> buf0, all async
    #pragma unroll
    for (int j = 0; j < 6; ++j) {
        int sig = j * 256 + tid;
        int r = sig / 24, cs = sig - r * 24;
        int ch = (cs & 24) | ((cs & 7) ^ (r & 7));
        async16(q + (size_t)(q0 + r) * QB_N + h * HD_QK + ch * 8,
                sm + 10240 + (j * 256 + wbase) * 8);
    }
    #pragma unroll
    for (int j = 0; j < 3; ++j) async16(kf_h + koff[j], sm + (j * 256 + wbase) * 8);
    #pragma unroll
    for (int j = 0; j < 2; ++j) async16(vt_h + voff[j], sm + 6144 + (j * 256 + wbase) * 8);
    __syncthreads();

    // Q fragments
    half8 qf[6];
    const int qrow = w * 16 + l15;
    #pragma unroll
    for (int kd = 0; kd < 6; ++kd) {
        int c = kd * 4 + quad;
        int cs = (c & 24) | ((c & 7) ^ (qrow & 7));
        qf[kd] = *(const half8*)&sm[10240 + (qrow * 24 + cs) * 8];
    }

    floatx4 o[8] = {};
    float m_i[4], l_i[4];
    #pragma unroll
    for (int r = 0; r < 4; ++r) { m_i[r] = -1e30f; l_i[r] = 0.f; }

    const int qrow_min = q0 + w * 16;
    const int ntiles = q0 / 32 + 2;
    f16* Pw = sm + 22528 + w * 640;

    for (int kt = 0; kt < ntiles; ++kt) {
        const int cur = kt & 1;
        __syncthreads();          // all waves done with buf[1-cur]; buf[cur] loads drained
        if (kt + 1 < ntiles) {    // prefetch next tile into buf[1-cur]
            const int nxt = 1 - cur;
            const int k0n = (kt + 1) * 32;
            f16* kb = sm + (nxt ? 10240 : 0);
            f16* vb = sm + (nxt ? 16384 : 6144);
            const f16* kg = kf_h + (size_t)k0n * HD_QK;
            const f16* vg = vt_h + k0n;
            #pragma unroll
            for (int j = 0; j < 3; ++j) async16(kg + koff[j], kb + (j * 256 + wbase) * 8);
            #pragma unroll
            for (int j = 0; j < 2; ++j) async16(vg + voff[j], vb + (j * 256 + wbase) * 8);
        }
        const int k0 = kt * 32;
        if (k0 > qrow_min + 15) continue;   // causally done for this wave

        const f16* kb = sm + (cur ? 10240 : 0);
        const f16* vb = sm + (cur ? 16384 : 6144);

        // QK^T (16 x 32)
        floatx4 s0 = {}, s1 = {};
        #pragma unroll
        for (int kd = 0; kd < 6; ++kd) {
            int c = kd * 4 + quad;
            int cs = (c & 24) | ((c & 7) ^ (l15 & 7));
            half8 b0 = *(const half8*)&kb[(l15 * 24 + cs) * 8];
            half8 b1 = *(const half8*)&kb[((l15 + 16) * 24 + cs) * 8];
            s0 = __builtin_amdgcn_mfma_f32_16x16x32_f16(qf[kd], b0, s0, 0, 0, 0);
            s1 = __builtin_amdgcn_mfma_f32_16x16x32_f16(qf[kd], b1, s1, 0, 0, 0);
        }

        // mask + scale (log2 domain) + row-max
        const bool nm = (k0 + 31 > qrow_min);
        float mt[4];
        #pragma unroll
        for (int r = 0; r < 4; ++r) {
            float v0 = s0[r] * scale2, v1 = s1[r] * scale2;
            if (nm) {
                int row = qrow_min + quad * 4 + r;
                if (k0 + l15 > row)      v0 = -1e30f;
                if (k0 + 16 + l15 > row) v1 = -1e30f;
            }
            s0[r] = v0; s1[r] = v1;
            mt[r] = fmaxf(v0, v1);
        }
        #pragma unroll
        for (int r = 0; r < 4; ++r) {
            mt[r] = fmaxf(mt[r], __shfl_xor(mt[r], 1));
            mt[r] = fmaxf(mt[r], __shfl_xor(mt[r], 2));
            mt[r] = fmaxf(mt[r], __shfl_xor(mt[r], 4));
            mt[r] = fmaxf(mt[r], __shfl_xor(mt[r], 8));
        }
        float alpha[4], ps[4];
        #pragma unroll
        for (int r = 0; r < 4; ++r) {
            float mn = fmaxf(m_i[r], mt[r]);
            alpha[r] = __builtin_exp2f(m_i[r] - mn);
            m_i[r] = mn;
            float p0 = __builtin_exp2f(s0[r] - mn);
            float p1 = __builtin_exp2f(s1[r] - mn);
            s0[r] = p0; s1[r] = p1;
            ps[r] = p0 + p1;
        }
        #pragma unroll
        for (int r = 0; r < 4; ++r) {
            ps[r] += __shfl_xor(ps[r], 1);
            ps[r] += __shfl_xor(ps[r], 2);
            ps[r] += __shfl_xor(ps[r], 4);
            ps[r] += __shfl_xor(ps[r], 8);
            l_i[r] = l_i[r] * alpha[r] + ps[r];
        }

        // P: C-layout -> wave-private LDS
        #pragma unroll
        for (int r = 0; r < 4; ++r) {
            Pw[(quad * 4 + r) * 40 + l15]      = (f16)s0[r];
            Pw[(quad * 4 + r) * 40 + 16 + l15] = (f16)s1[r];
        }

        // rescale O
        #pragma unroll
        for (int nb = 0; nb < 8; ++nb)
            #pragma unroll
            for (int r = 0; r < 4; ++r) o[nb][r] *= alpha[r];

        // PV
        half8 pa = *(const half8*)&Pw[l15 * 40 + quad * 8];
        #pragma unroll
        for (int nb = 0; nb < 8; ++nb) {
            int rv = nb * 16 + l15;
            int sig = rv * 4 + (quad ^ ((l15 >> 1) & 3));
            half8 vv = *(const half8*)&vb[sig * 8];
            o[nb] = __builtin_amdgcn_mfma_f32_16x16x32_f16(pa, vv, o[nb], 0, 0, 0);
        }
    }

    float inv[4];
    #pragma unroll
    for (int r = 0; r < 4; ++r) inv[r] = 1.f / l_i[r];
    #pragma unroll
    for (int nb = 0; nb < 8; ++nb) {
        #pragma unroll
        for (int r = 0; r < 4; ++r) {
            int row = q0 + w * 16 + quad * 4 + r;
            attn[(size_t)row * (NH * DV) + h * DV + nb * 16 + l15] =
                (f16)(o[nb][r] * inv[r]);
        }
    }
}

// ---------------------------------------------------------------------------
// Launch
// ---------------------------------------------------------------------------
extern "C" void kernel_launch(void* const* d_in, const int* in_sizes, int n_in,
                              void* d_out, int out_size, void* d_ws, size_t ws_size,
                              hipStream_t stream)
{
    const float* hidden   = (const float*)d_in[0];
    const float* w_kv_a   = (const float*)d_in[1];
    const float* q_gamma  = (const float*)d_in[2];
    const float* w_qb     = (const float*)d_in[3];
    const float* kv_gamma = (const float*)d_in[4];
    const float* w_kvb    = (const float*)d_in[5];
    const float* w_o      = (const float*)d_in[6];
    float* out = (float*)d_out;

    char* p = (char*)d_ws;
    f16* hid_h   = (f16*)p;  p += (size_t)2048 * 2048 * 2;
    f16* wkva_t  = (f16*)p;  p += (size_t)2176 * 2048 * 2;
    f16* wqb_t   = (f16*)p;  p += (size_t)3072 * 1536 * 2;
    f16* wkvb_t  = (f16*)p;  p += (size_t)4096 * 512 * 2;
    f16* wo_t    = (f16*)p;  p += (size_t)2048 * 2048 * 2;
    float* fused = (float*)p; p += (size_t)2048 * FPAD * 4;
    f16* q_n     = (f16*)p;  p += (size_t)2048 * QL * 2;
    f16* qbuf    = (f16*)p;  p += (size_t)2048 * QB_N * 2;
    f16* kv_n    = (f16*)p;  p += (size_t)2048 * KL * 2;
    f16* kvbuf   = (f16*)p;  p += (size_t)2048 * KVB_N * 2;
    f16* kpe     = (f16*)p;  p += (size_t)2048 * DR * 2;
    f16* attnb   = (f16*)p;  p += (size_t)2048 * 2048 * 2;

    // aliases onto dead regions:
    //   kfull [16][2048][192] f16 (12.6 MB) <- hid_h+wkva_t (dead after gemm1)
    //   vt    [16][128][2048] f16 ( 8.4 MB) <- fused (dead after rmsnorm/rope)
    f16* kfull = hid_h;
    f16* vt    = (f16*)fused;

    dim3 blk(256);

    cvt_f16_k<<<(2048 * 2048 / 4 + 255) / 256, blk, 0, stream>>>(hidden, hid_h, 2048 * 2048 / 4);
    tconv_k<<<dim3(2176 / 32, 2048 / 32), blk, 0, stream>>>(w_kv_a, wkva_t, 2048, FUSED_N);
    tconv_k<<<dim3(3072 / 32, 1536 / 32), blk, 0, stream>>>(w_qb,   wqb_t,  1536, QB_N);
    tconv_k<<<dim3(4096 / 32,  512 / 32), blk, 0, stream>>>(w_kvb,  wkvb_t,  512, KVB_N);
    tconv_k<<<dim3(2048 / 32, 2048 / 32), blk, 0, stream>>>(w_o,    wo_t,   2048, 2048);

    gemm_mfma<0><<<dim3(FPAD / 128, 2048 / 128), blk, 0, stream>>>(
        hid_h, wkva_t, fused, 2048, FPAD, 2048);

    rmsnorm_k<<<2048, blk, 0, stream>>>(fused, FPAD, QL, q_gamma, q_n);
    rmsnorm_k<<<2048, blk, 0, stream>>>(fused + QL, FPAD, KL, kv_gamma, kv_n);

    gemm_mfma<1><<<dim3(QB_N / 128, 2048 / 128), blk, 0, stream>>>(
        q_n, wqb_t, qbuf, 2048, QB_N, QL);
    gemm_mfma<1><<<dim3(KVB_N / 128, 2048 / 128), blk, 0, stream>>>(
        kv_n, wkvb_t, kvbuf, 2048, KVB_N, KL);

    rope_q_k<<<dim3(2048, 4), blk, 0, stream>>>(qbuf);
    rope_kpe_k<<<2048, dim3(64), 0, stream>>>(fused, kpe);

    kfull_k<<<16 * 2048 * 24 / 256, blk, 0, stream>>>(kvbuf, kpe, kfull);
    vt_k<<<dim3(2048 / 32, 128 / 32, NH), blk, 0, stream>>>(kvbuf, vt);

    attn_mfma_k<<<dim3(2048 / 64, NH), blk, 0, stream>>>(qbuf, kfull, vt, attnb);

    gemm_mfma<0><<<dim3(2048 / 128, 2048 / 128), blk, 0, stream>>>(
        attnb, wo_t, out, 2048, 2048, 2048);
}

// Round 6
// 391.799 us; speedup vs baseline: 10.0755x; 1.0280x over previous
//
#include <hip/hip_runtime.h>
#include <math.h>

#define S_LEN 2048
#define NH 16
#define DN 128
#define DR 64
#define DV 128
#define QL 1536
#define KL 512
#define FUSED_N 2112
#define FPAD 2176            // fused padded to 17*128 for uniform GEMM tiles
#define QB_N 3072
#define KVB_N 4096
#define HD_QK 192
#define EPS_RMS 1e-6f

typedef _Float16 f16;
typedef _Float16 half8 __attribute__((ext_vector_type(8)));
typedef _Float16 half4 __attribute__((ext_vector_type(4)));
typedef float floatx4 __attribute__((ext_vector_type(4)));

// ---------------------------------------------------------------------------
// fp32 -> f16 elementwise (4/thread)
// ---------------------------------------------------------------------------
__global__ __launch_bounds__(256) void cvt_f16_k(const float* __restrict__ in,
                                                 f16* __restrict__ out, int n4)
{
    int i = blockIdx.x * 256 + threadIdx.x;
    if (i < n4) {
        float4 v = ((const float4*)in)[i];
        half4 h;
        h[0] = (f16)v.x; h[1] = (f16)v.y; h[2] = (f16)v.z; h[3] = (f16)v.w;
        ((half4*)out)[i] = h;
    }
}

// ---------------------------------------------------------------------------
// fp32 [K][N] -> f16 B^T [Npad][K]; rows n>=N zero-filled.
// ---------------------------------------------------------------------------
__global__ __launch_bounds__(256) void tconv_k(const float* __restrict__ in,
                                               f16* __restrict__ out,
                                               int K, int N)
{
    __shared__ float t[32][33];
    const int k0 = blockIdx.y * 32, n0 = blockIdx.x * 32;
    const int c = threadIdx.x & 31, r8 = threadIdx.x >> 5;
    #pragma unroll
    for (int i = 0; i < 4; ++i) {
        int r = r8 + i * 8;
        int gc = n0 + c;
        t[r][c] = (gc < N) ? in[(size_t)(k0 + r) * N + gc] : 0.f;
    }
    __syncthreads();
    #pragma unroll
    for (int i = 0; i < 4; ++i) {
        int r = r8 + i * 8;     // local n
        out[(size_t)(n0 + r) * K + k0 + c] = (f16)t[c][r];
    }
}

// ---------------------------------------------------------------------------
// f16 MFMA GEMM: C[M,N] = A[M,K] @ Bt[N,K]^T.  128x128 tile, BK=64.
// ---------------------------------------------------------------------------
__device__ __forceinline__ void async16(const f16* gp, f16* lp)
{
    __builtin_amdgcn_global_load_lds(
        (const __attribute__((address_space(1))) void*)gp,
        (__attribute__((address_space(3))) void*)lp, 16, 0, 0);
}

template <int OUT_F16>
__global__ __launch_bounds__(256) void gemm_mfma(
    const f16* __restrict__ A,   // [M][K]
    const f16* __restrict__ Bt,  // [N][K]
    void* __restrict__ Cv, int M, int N, int K)
{
    __shared__ f16 As[128 * 64];
    __shared__ f16 Bs[128 * 64];

    const int tid = threadIdx.x;
    const int wv = tid >> 6, lane = tid & 63;
    const int quad = lane >> 4, l15 = lane & 15;
    const int wr = wv >> 1, wc = wv & 1;
    const int bm = blockIdx.y * 128, bn = blockIdx.x * 128;
    const int srow = lane >> 3;      // 0..7
    const int sc = lane & 7;         // slot chunk 0..7

    floatx4 acc[4][4] = {};

    for (int k0 = 0; k0 < K; k0 += 64) {
        #pragma unroll
        for (int t = 0; t < 4; ++t) {
            int rl = wv * 32 + t * 8 + srow;     // local row 0..127
            int ch = sc ^ (rl & 7);              // data chunk for this slot
            async16(A  + (size_t)(bm + rl) * K + k0 + ch * 8,
                    &As[(wv * 32 + t * 8) * 64]);
            async16(Bt + (size_t)(bn + rl) * K + k0 + ch * 8,
                    &Bs[(wv * 32 + t * 8) * 64]);
        }
        __syncthreads();

        #pragma unroll
        for (int ks = 0; ks < 2; ++ks) {
            half8 av[4], bv[4];
            #pragma unroll
            for (int i = 0; i < 4; ++i) {
                int m = wr * 64 + i * 16 + l15;
                av[i] = *(const half8*)&As[m * 64 + ((ks * 4 + quad) ^ (m & 7)) * 8];
            }
            #pragma unroll
            for (int j = 0; j < 4; ++j) {
                int n = wc * 64 + j * 16 + l15;
                bv[j] = *(const half8*)&Bs[n * 64 + ((ks * 4 + quad) ^ (n & 7)) * 8];
            }
            #pragma unroll
            for (int i = 0; i < 4; ++i)
                #pragma unroll
                for (int j = 0; j < 4; ++j)
                    acc[i][j] = __builtin_amdgcn_mfma_f32_16x16x32_f16(
                        av[i], bv[j], acc[i][j], 0, 0, 0);
        }
        __syncthreads();
    }

    #pragma unroll
    for (int i = 0; i < 4; ++i) {
        int rbase = bm + wr * 64 + i * 16 + quad * 4;
        #pragma unroll
        for (int j = 0; j < 4; ++j) {
            int cidx = bn + wc * 64 + j * 16 + l15;
            #pragma unroll
            for (int rr = 0; rr < 4; ++rr) {
                if (OUT_F16)
                    ((f16*)Cv)[(size_t)(rbase + rr) * N + cidx] = (f16)acc[i][j][rr];
                else
                    ((float*)Cv)[(size_t)(rbase + rr) * N + cidx] = acc[i][j][rr];
            }
        }
    }
}

// ---------------------------------------------------------------------------
// RMSNorm: fp32 strided in -> f16 compact out
// ---------------------------------------------------------------------------
__global__ __launch_bounds__(256) void rmsnorm_k(
    const float* __restrict__ in, int stride, int ncols,
    const float* __restrict__ gamma, f16* __restrict__ out)
{
    const int row = blockIdx.x;
    const float* x = in + (size_t)row * stride;

    float ss = 0.f;
    for (int c = threadIdx.x; c < ncols; c += 256) {
        float v = x[c];
        ss += v * v;
    }
    #pragma unroll
    for (int off = 32; off > 0; off >>= 1) ss += __shfl_down(ss, off);

    __shared__ float warp_s[4];
    __shared__ float scale_s;
    const int wid = threadIdx.x >> 6;
    if ((threadIdx.x & 63) == 0) warp_s[wid] = ss;
    __syncthreads();
    if (threadIdx.x == 0) {
        float t = warp_s[0] + warp_s[1] + warp_s[2] + warp_s[3];
        scale_s = rsqrtf(t / (float)ncols + EPS_RMS);
    }
    __syncthreads();
    const float sc = scale_s;
    for (int c = threadIdx.x; c < ncols; c += 256)
        out[(size_t)row * ncols + c] = (f16)(x[c] * gamma[c] * sc);
}

// ---------------------------------------------------------------------------
// RoPE
// ---------------------------------------------------------------------------
__device__ __forceinline__ float rope_one(int s, int d, float x, float other)
{
    const int j = d & 31;
    const float invf = expf(-0.28782313662425572f * (float)j); // 10000^(-j/32)
    const float ang = (float)s * invf;
    float sn, cs;
    sincosf(ang, &sn, &cs);
    float rot = (d < 32) ? -other : other;
    return x * cs + rot * sn;
}

// grid (S, 4), block 256: each wave rotates one head's q_pe
__global__ __launch_bounds__(256) void rope_q_k(f16* __restrict__ q)
{
    const int s = blockIdx.x;
    const int h = blockIdx.y * 4 + (threadIdx.x >> 6);
    const int d = threadIdx.x & 63;
    f16* base = q + (size_t)s * QB_N + h * HD_QK + DN;
    float x = (float)base[d];
    float other = (float)((d < 32) ? base[d + 32] : base[d - 32]);
    base[d] = (f16)rope_one(s, d, x, other);
}

// ---------------------------------------------------------------------------
// kfull[h][s][192] = concat(k_nope, rope(k_pe)); k_pe rotated inline from
// fused fp32.  MUST run before vt_k (vt aliases the fused region).
// ---------------------------------------------------------------------------
__global__ __launch_bounds__(256) void kfull_k(const f16* __restrict__ kv,
                                               const float* __restrict__ fused,
                                               f16* __restrict__ kfull)
{
    int n = blockIdx.x * 256 + threadIdx.x;   // < 16*2048*24
    int c8 = n % 24;
    int s = (n / 24) & 2047;
    int h = n / (24 * 2048);
    half8 v;
    if (c8 < 16) {
        v = *(const half8*)&kv[(size_t)s * KVB_N + h * 256 + c8 * 8];
    } else {
        const float* src = fused + (size_t)s * FPAD + (QL + KL);
        int dbase = (c8 - 16) * 8;
        #pragma unroll
        for (int j = 0; j < 8; ++j) {
            int d = dbase + j;
            float x = src[d];
            float other = src[(d < 32) ? d + 32 : d - 32];
            v[j] = (f16)rope_one(s, d, x, other);
        }
    }
    *(half8*)&kfull[((size_t)h * S_LEN + s) * HD_QK + c8 * 8] = v;
}

// ---------------------------------------------------------------------------
// vt[h][d][s] = kvbuf[s][h*256 + 128 + d]   (V transpose, 32x32 tiles)
// ---------------------------------------------------------------------------
__global__ __launch_bounds__(256) void vt_k(const f16* __restrict__ kv,
                                            f16* __restrict__ vt)
{
    __shared__ f16 t[32][33];
    const int s0 = blockIdx.x * 32, d0 = blockIdx.y * 32, h = blockIdx.z;
    const int tid = threadIdx.x;
    {
        const int c = tid & 31, rb = tid >> 5;
        #pragma unroll
        for (int i = 0; i < 4; ++i) {
            int r = rb + i * 8;  // s offset
            t[r][c] = kv[(size_t)(s0 + r) * KVB_N + h * 256 + 128 + d0 + c];
        }
    }
    __syncthreads();
    {
        const int d = tid >> 3, s4 = tid & 7;
        half4 v;
        v[0] = t[s4 * 4 + 0][d];
        v[1] = t[s4 * 4 + 1][d];
        v[2] = t[s4 * 4 + 2][d];
        v[3] = t[s4 * 4 + 3][d];
        *(half4*)&vt[((size_t)h * DV + d0 + d) * S_LEN + s0 + s4 * 4] = v;
    }
}

// ---------------------------------------------------------------------------
// MFMA flash attention (causal), split-K=2 (flash-decoding) + dbuf async
// staging.  grid (32, 16, 2): x->qb (balance-remapped), y->head, z->K-half.
// Half z=0: tiles [0, qb+1); z=1: [qb+1, 2qb+2)  (T = 2qb+2 always even).
// Per-half online softmax; partials: normalized O (f16) + (m,l) fp32.
// Row-sum via all-ones-B MFMA (l lives in the ACC file; no shuffles).
//
// LDS map (f16 units, total 25088 = 50 KB):
//   Ks0 [0,6144)  V0 [6144,10240)  | Ks1 [10240,16384) V1 [16384,20480)
//   Q stage [10240,22528) (pre-loop only) | P [22528,25088)
// ---------------------------------------------------------------------------
__global__ __launch_bounds__(256) void attn_mfma_k(
    const f16* __restrict__ q,      // [S][3072]
    const f16* __restrict__ kfull,  // [NH][S][192]
    const f16* __restrict__ vt,     // [NH][128][S]
    f16* __restrict__ part_o,       // [2][S][2048]
    float* __restrict__ part_ml)    // [2][NH][S][2]
{
    __shared__ f16 sm[25088];

    const int tid = threadIdx.x;
    const int w = tid >> 6, lane = tid & 63;
    const int quad = lane >> 4, l15 = lane & 15;
    const int wbase = w * 64;
    const int h = blockIdx.y;
    const int z = blockIdx.z;
    const int qb = (blockIdx.y < 8) ? (int)blockIdx.x : 31 - (int)blockIdx.x;
    const int q0 = qb * 64;
    const int kt_begin = z ? (qb + 1) : 0;
    const int kt_end   = z ? (2 * qb + 2) : (qb + 1);
    const float scale2 = 0.10411755f;   // (1/sqrt(192)) * log2(e)

    const f16* kf_h = kfull + (size_t)h * S_LEN * HD_QK;
    const f16* vt_h = vt + (size_t)h * DV * S_LEN;

    // staging slot decodes (k0-independent)
    int koff[3];
    #pragma unroll
    for (int j = 0; j < 3; ++j) {
        int sig = j * 256 + tid;
        int r = sig / 24, cs = sig - r * 24;
        int ch = (cs & 24) | ((cs & 7) ^ (r & 7));
        koff[j] = r * HD_QK + ch * 8;
    }
    int voff[2];
    #pragma unroll
    for (int j = 0; j < 2; ++j) {
        int sig = j * 256 + tid;
        int rv = sig >> 2, c = (sig & 3) ^ ((rv >> 1) & 3);
        voff[j] = rv * S_LEN + c * 8;
    }

    // stage Q (64x192) -> sm+10240, and first K/V tile -> buf0, all async
    #pragma unroll
    for (int j = 0; j < 6; ++j) {
        int sig = j * 256 + tid;
        int r = sig / 24, cs = sig - r * 24;
        int ch = (cs & 24) | ((cs & 7) ^ (r & 7));
        async16(q + (size_t)(q0 + r) * QB_N + h * HD_QK + ch * 8,
                sm + 10240 + (j * 256 + wbase) * 8);
    }
    {
        const f16* kg = kf_h + (size_t)kt_begin * 32 * HD_QK;
        const f16* vg = vt_h + kt_begin * 32;
        #pragma unroll
        for (int j = 0; j < 3; ++j) async16(kg + koff[j], sm + (j * 256 + wbase) * 8);
        #pragma unroll
        for (int j = 0; j < 2; ++j) async16(vg + voff[j], sm + 6144 + (j * 256 + wbase) * 8);
    }
    __syncthreads();

    // Q fragments
    half8 qf[6];
    const int qrow = w * 16 + l15;
    #pragma unroll
    for (int kd = 0; kd < 6; ++kd) {
        int c = kd * 4 + quad;
        int cs = (c & 24) | ((c & 7) ^ (qrow & 7));
        qf[kd] = *(const half8*)&sm[10240 + (qrow * 24 + cs) * 8];
    }

    half8 ones_h;
    #pragma unroll
    for (int j = 0; j < 8; ++j) ones_h[j] = (f16)1.0f;

    floatx4 o[8] = {};
    floatx4 o_l = {};
    float m_i[4];
    #pragma unroll
    for (int r = 0; r < 4; ++r) m_i[r] = -1e30f;

    const int qrow_min = q0 + w * 16;
    f16* Pw = sm + 22528 + w * 640;

    for (int kt = kt_begin; kt < kt_end; ++kt) {
        const int cur = (kt - kt_begin) & 1;
        __syncthreads();          // buf[1-cur] free; buf[cur] loads drained
        if (kt + 1 < kt_end) {    // prefetch next tile into buf[1-cur]
            const int nxt = 1 - cur;
            const int k0n = (kt + 1) * 32;
            f16* kb = sm + (nxt ? 10240 : 0);
            f16* vb = sm + (nxt ? 16384 : 6144);
            const f16* kg = kf_h + (size_t)k0n * HD_QK;
            const f16* vg = vt_h + k0n;
            #pragma unroll
            for (int j = 0; j < 3; ++j) async16(kg + koff[j], kb + (j * 256 + wbase) * 8);
            #pragma unroll
            for (int j = 0; j < 2; ++j) async16(vg + voff[j], vb + (j * 256 + wbase) * 8);
        }
        const int k0 = kt * 32;
        if (k0 > qrow_min + 15) continue;   // causally done for this wave

        const f16* kb = sm + (cur ? 10240 : 0);
        const f16* vb = sm + (cur ? 16384 : 6144);

        // QK^T (16 x 32)
        floatx4 s0 = {}, s1 = {};
        #pragma unroll
        for (int kd = 0; kd < 6; ++kd) {
            int c = kd * 4 + quad;
            int cs = (c & 24) | ((c & 7) ^ (l15 & 7));
            half8 b0 = *(const half8*)&kb[(l15 * 24 + cs) * 8];
            half8 b1 = *(const half8*)&kb[((l15 + 16) * 24 + cs) * 8];
            s0 = __builtin_amdgcn_mfma_f32_16x16x32_f16(qf[kd], b0, s0, 0, 0, 0);
            s1 = __builtin_amdgcn_mfma_f32_16x16x32_f16(qf[kd], b1, s1, 0, 0, 0);
        }

        // mask + scale (log2 domain) + row-max (16-lane shuffles)
        const bool nm = (k0 + 31 > qrow_min);
        float mt[4];
        #pragma unroll
        for (int r = 0; r < 4; ++r) {
            float v0 = s0[r] * scale2, v1 = s1[r] * scale2;
            if (nm) {
                int row = qrow_min + quad * 4 + r;
                if (k0 + l15 > row)      v0 = -1e30f;
                if (k0 + 16 + l15 > row) v1 = -1e30f;
            }
            s0[r] = v0; s1[r] = v1;
            mt[r] = fmaxf(v0, v1);
        }
        #pragma unroll
        for (int r = 0; r < 4; ++r) {
            mt[r] = fmaxf(mt[r], __shfl_xor(mt[r], 1));
            mt[r] = fmaxf(mt[r], __shfl_xor(mt[r], 2));
            mt[r] = fmaxf(mt[r], __shfl_xor(mt[r], 4));
            mt[r] = fmaxf(mt[r], __shfl_xor(mt[r], 8));
        }
        float alpha[4];
        #pragma unroll
        for (int r = 0; r < 4; ++r) {
            float mn = fmaxf(m_i[r], mt[r]);
            alpha[r] = __builtin_exp2f(m_i[r] - mn);
            m_i[r] = mn;
            s0[r] = __builtin_exp2f(s0[r] - mn);
            s1[r] = __builtin_exp2f(s1[r] - mn);
        }

        // P: C-layout -> wave-private LDS
        #pragma unroll
        for (int r = 0; r < 4; ++r) {
            Pw[(quad * 4 + r) * 40 + l15]      = (f16)s0[r];
            Pw[(quad * 4 + r) * 40 + 16 + l15] = (f16)s1[r];
        }

        // rescale O and l
        #pragma unroll
        for (int nb = 0; nb < 8; ++nb)
            #pragma unroll
            for (int r = 0; r < 4; ++r) o[nb][r] *= alpha[r];
        #pragma unroll
        for (int r = 0; r < 4; ++r) o_l[r] *= alpha[r];

        // PV (+ row-sum via ones-B MFMA; no cross-lane ops)
        half8 pa = *(const half8*)&Pw[l15 * 40 + quad * 8];
        o_l = __builtin_amdgcn_mfma_f32_16x16x32_f16(pa, ones_h, o_l, 0, 0, 0);
        #pragma unroll
        for (int nb = 0; nb < 8; ++nb) {
            int rv = nb * 16 + l15;
            int sig = rv * 4 + (quad ^ ((l15 >> 1) & 3));
            half8 vv = *(const half8*)&vb[sig * 8];
            o[nb] = __builtin_amdgcn_mfma_f32_16x16x32_f16(pa, vv, o[nb], 0, 0, 0);
        }
    }

    float inv[4];
    #pragma unroll
    for (int r = 0; r < 4; ++r) inv[r] = (o_l[r] > 0.f) ? 1.f / o_l[r] : 0.f;

    f16* po = part_o + (size_t)z * S_LEN * 2048;
    #pragma unroll
    for (int nb = 0; nb < 8; ++nb) {
        #pragma unroll
        for (int r = 0; r < 4; ++r) {
            int row = q0 + w * 16 + quad * 4 + r;
            po[(size_t)row * (NH * DV) + h * DV + nb * 16 + l15] =
                (f16)(o[nb][r] * inv[r]);
        }
    }
    if (l15 == 0) {
        #pragma unroll
        for (int r = 0; r < 4; ++r) {
            int row = q0 + w * 16 + quad * 4 + r;
            float* ml = part_ml + (((size_t)z * NH + h) * S_LEN + row) * 2;
            ml[0] = m_i[r];
            ml[1] = o_l[r];
        }
    }
}

// ---------------------------------------------------------------------------
// Combine the two split-K halves:  O = (w0*O0n + w1*O1n),  wz = lz*2^(mz-M).
// ---------------------------------------------------------------------------
__global__ __launch_bounds__(256) void attn_comb_k(
    const f16* __restrict__ part_o, const float* __restrict__ part_ml,
    f16* __restrict__ attnb)
{
    int g = blockIdx.x * 256 + threadIdx.x;       // < 2048*2048/8
    int h = (g >> 4) & 15;
    int s = g >> 8;
    const float* ml0 = part_ml + ((size_t)h * S_LEN + s) * 2;
    const float* ml1 = part_ml + (((size_t)NH + h) * S_LEN + s) * 2;
    float m0 = ml0[0], l0 = ml0[1];
    float m1 = ml1[0], l1 = ml1[1];
    float M = fmaxf(m0, m1);
    float w0 = l0 * __builtin_exp2f(m0 - M);
    float w1 = l1 * __builtin_exp2f(m1 - M);
    float inv = 1.f / (w0 + w1);
    w0 *= inv; w1 *= inv;
    half8 p0 = *(const half8*)&part_o[(size_t)g * 8];
    half8 p1 = *(const half8*)&part_o[(size_t)(524288 + g) * 8];
    half8 r;
    #pragma unroll
    for (int j = 0; j < 8; ++j)
        r[j] = (f16)(w0 * (float)p0[j] + w1 * (float)p1[j]);
    *(half8*)&attnb[(size_t)g * 8] = r;
}

// ---------------------------------------------------------------------------
// Launch
// ---------------------------------------------------------------------------
extern "C" void kernel_launch(void* const* d_in, const int* in_sizes, int n_in,
                              void* d_out, int out_size, void* d_ws, size_t ws_size,
                              hipStream_t stream)
{
    const float* hidden   = (const float*)d_in[0];
    const float* w_kv_a   = (const float*)d_in[1];
    const float* q_gamma  = (const float*)d_in[2];
    const float* w_qb     = (const float*)d_in[3];
    const float* kv_gamma = (const float*)d_in[4];
    const float* w_kvb    = (const float*)d_in[5];
    const float* w_o      = (const float*)d_in[6];
    float* out = (float*)d_out;

    char* p = (char*)d_ws;
    f16* hid_h   = (f16*)p;  p += (size_t)2048 * 2048 * 2;
    f16* wkva_t  = (f16*)p;  p += (size_t)2176 * 2048 * 2;
    f16* wqb_t   = (f16*)p;  p += (size_t)3072 * 1536 * 2;
    f16* wkvb_t  = (f16*)p;  p += (size_t)4096 * 512 * 2;
    f16* wo_t    = (f16*)p;  p += (size_t)2048 * 2048 * 2;
    float* fused = (float*)p; p += (size_t)2048 * FPAD * 4;
    f16* q_n     = (f16*)p;  p += (size_t)2048 * QL * 2;
    f16* qbuf    = (f16*)p;  p += (size_t)2048 * QB_N * 2;
    f16* kv_n    = (f16*)p;  p += (size_t)2048 * KL * 2;
    f16* kvbuf   = (f16*)p;  p += (size_t)2048 * KVB_N * 2;
    f16* attnb   = (f16*)p;  p += (size_t)2048 * 2048 * 2;
    f16* part_o  = (f16*)p;  p += (size_t)2 * 2048 * 2048 * 2;
    float* part_ml = (float*)p; p += (size_t)2 * NH * 2048 * 2 * 4;

    // aliases onto dead regions:
    //   kfull [16][2048][192] f16 (12.6 MB) <- hid_h+wkva_t (dead after gemm1)
    //   vt    [16][128][2048] f16 ( 8.4 MB) <- fused (dead after kfull_k)
    f16* kfull = hid_h;
    f16* vt    = (f16*)fused;

    dim3 blk(256);

    cvt_f16_k<<<(2048 * 2048 / 4 + 255) / 256, blk, 0, stream>>>(hidden, hid_h, 2048 * 2048 / 4);
    tconv_k<<<dim3(2176 / 32, 2048 / 32), blk, 0, stream>>>(w_kv_a, wkva_t, 2048, FUSED_N);
    tconv_k<<<dim3(3072 / 32, 1536 / 32), blk, 0, stream>>>(w_qb,   wqb_t,  1536, QB_N);
    tconv_k<<<dim3(4096 / 32,  512 / 32), blk, 0, stream>>>(w_kvb,  wkvb_t,  512, KVB_N);
    tconv_k<<<dim3(2048 / 32, 2048 / 32), blk, 0, stream>>>(w_o,    wo_t,   2048, 2048);

    gemm_mfma<0><<<dim3(FPAD / 128, 2048 / 128), blk, 0, stream>>>(
        hid_h, wkva_t, fused, 2048, FPAD, 2048);

    rmsnorm_k<<<2048, blk, 0, stream>>>(fused, FPAD, QL, q_gamma, q_n);
    rmsnorm_k<<<2048, blk, 0, stream>>>(fused + QL, FPAD, KL, kv_gamma, kv_n);

    gemm_mfma<1><<<dim3(QB_N / 128, 2048 / 128), blk, 0, stream>>>(
        q_n, wqb_t, qbuf, 2048, QB_N, QL);
    gemm_mfma<1><<<dim3(KVB_N / 128, 2048 / 128), blk, 0, stream>>>(
        kv_n, wkvb_t, kvbuf, 2048, KVB_N, KL);

    rope_q_k<<<dim3(2048, 4), blk, 0, stream>>>(qbuf);

    // kfull (reads fused for k_pe rope) BEFORE vt_k (vt overwrites fused)
    kfull_k<<<16 * 2048 * 24 / 256, blk, 0, stream>>>(kvbuf, fused, kfull);
    vt_k<<<dim3(2048 / 32, 128 / 32, NH), blk, 0, stream>>>(kvbuf, vt);

    attn_mfma_k<<<dim3(32, NH, 2), blk, 0, stream>>>(qbuf, kfull, vt, part_o, part_ml);
    attn_comb_k<<<2048, blk, 0, stream>>>(part_o, part_ml, attnb);

    gemm_mfma<0><<<dim3(2048 / 128, 2048 / 128), blk, 0, stream>>>(
        attnb, wo_t, out, 2048, 2048, 2048);
}

// Round 7
// 356.638 us; speedup vs baseline: 11.0688x; 1.0986x over previous
//
#include <hip/hip_runtime.h>
#include <math.h>

#define S_LEN 2048
#define NH 16
#define DN 128
#define DR 64
#define DV 128
#define QL 1536
#define KL 512
#define FUSED_N 2112
#define FPAD 2176            // fused padded to 17*128 for uniform GEMM tiles
#define QB_N 3072
#define KVB_N 4096
#define HD_QK 192
#define EPS_RMS 1e-6f

typedef _Float16 f16;
typedef _Float16 half8 __attribute__((ext_vector_type(8)));
typedef _Float16 half4 __attribute__((ext_vector_type(4)));
typedef float floatx4 __attribute__((ext_vector_type(4)));

// ---------------------------------------------------------------------------
// fp32 -> f16 elementwise (4/thread)
// ---------------------------------------------------------------------------
__global__ __launch_bounds__(256) void cvt_f16_k(const float* __restrict__ in,
                                                 f16* __restrict__ out, int n4)
{
    int i = blockIdx.x * 256 + threadIdx.x;
    if (i < n4) {
        float4 v = ((const float4*)in)[i];
        half4 h;
        h[0] = (f16)v.x; h[1] = (f16)v.y; h[2] = (f16)v.z; h[3] = (f16)v.w;
        ((half4*)out)[i] = h;
    }
}

// ---------------------------------------------------------------------------
// fp32 [K][N] -> f16 B^T [Npad][K]; rows n>=N zero-filled.
// ---------------------------------------------------------------------------
__global__ __launch_bounds__(256) void tconv_k(const float* __restrict__ in,
                                               f16* __restrict__ out,
                                               int K, int N)
{
    __shared__ float t[32][33];
    const int k0 = blockIdx.y * 32, n0 = blockIdx.x * 32;
    const int c = threadIdx.x & 31, r8 = threadIdx.x >> 5;
    #pragma unroll
    for (int i = 0; i < 4; ++i) {
        int r = r8 + i * 8;
        int gc = n0 + c;
        t[r][c] = (gc < N) ? in[(size_t)(k0 + r) * N + gc] : 0.f;
    }
    __syncthreads();
    #pragma unroll
    for (int i = 0; i < 4; ++i) {
        int r = r8 + i * 8;     // local n
        out[(size_t)(n0 + r) * K + k0 + c] = (f16)t[c][r];
    }
}

// ---------------------------------------------------------------------------
// f16 MFMA GEMM: C[M,N] = A[M,K] @ Bt[N,K]^T.  128x128 tile, BK=64.
// Double-buffered async K-loop (one barrier per step): prefetch K-step s+1
// into buf[1-cur] right after the barrier, compute step s from buf[cur].
// At 1-2 blocks/CU this hides the L2 load latency the m97-style 2-barrier
// structure exposes.  LDS = 2 x (As+Bs) = 64 KB.
// ---------------------------------------------------------------------------
__device__ __forceinline__ void async16(const f16* gp, f16* lp)
{
    __builtin_amdgcn_global_load_lds(
        (const __attribute__((address_space(1))) void*)gp,
        (__attribute__((address_space(3))) void*)lp, 16, 0, 0);
}

template <int OUT_F16>
__global__ __launch_bounds__(256) void gemm_mfma(
    const f16* __restrict__ A,   // [M][K]
    const f16* __restrict__ Bt,  // [N][K]
    void* __restrict__ Cv, int M, int N, int K)
{
    __shared__ f16 sm[2][2][128 * 64];   // [buf][A/B][tile]

    const int tid = threadIdx.x;
    const int wv = tid >> 6, lane = tid & 63;
    const int quad = lane >> 4, l15 = lane & 15;
    const int wr = wv >> 1, wc = wv & 1;
    const int bm = blockIdx.y * 128, bn = blockIdx.x * 128;
    const int srow = lane >> 3;      // 0..7
    const int sc = lane & 7;         // slot chunk 0..7

    // k0-invariant staging offsets (global, in f16 elems) per t-slot
    size_t aoff[4], boff[4];
    int ldst[4];
    #pragma unroll
    for (int t = 0; t < 4; ++t) {
        int rl = wv * 32 + t * 8 + srow;
        int ch = sc ^ (rl & 7);
        aoff[t] = (size_t)(bm + rl) * K + ch * 8;
        boff[t] = (size_t)(bn + rl) * K + ch * 8;
        ldst[t] = (wv * 32 + t * 8) * 64;
    }

    // stage step 0 into buf 0
    #pragma unroll
    for (int t = 0; t < 4; ++t) {
        async16(A  + aoff[t], &sm[0][0][ldst[t]]);
        async16(Bt + boff[t], &sm[0][1][ldst[t]]);
    }

    floatx4 acc[4][4] = {};
    const int nsteps = K >> 6;

    for (int step = 0; step < nsteps; ++step) {
        const int cur = step & 1;
        __syncthreads();                 // buf[cur] loads drained; buf[1-cur] free
        if (step + 1 < nsteps) {
            const int k0n = (step + 1) << 6;
            f16* Ab = sm[1 - cur][0];
            f16* Bb = sm[1 - cur][1];
            #pragma unroll
            for (int t = 0; t < 4; ++t) {
                async16(A  + aoff[t] + k0n, Ab + ldst[t]);
                async16(Bt + boff[t] + k0n, Bb + ldst[t]);
            }
        }
        const f16* As = sm[cur][0];
        const f16* Bs = sm[cur][1];

        #pragma unroll
        for (int ks = 0; ks < 2; ++ks) {
            half8 av[4], bv[4];
            #pragma unroll
            for (int i = 0; i < 4; ++i) {
                int m = wr * 64 + i * 16 + l15;
                av[i] = *(const half8*)&As[m * 64 + ((ks * 4 + quad) ^ (m & 7)) * 8];
            }
            #pragma unroll
            for (int j = 0; j < 4; ++j) {
                int n = wc * 64 + j * 16 + l15;
                bv[j] = *(const half8*)&Bs[n * 64 + ((ks * 4 + quad) ^ (n & 7)) * 8];
            }
            #pragma unroll
            for (int i = 0; i < 4; ++i)
                #pragma unroll
                for (int j = 0; j < 4; ++j)
                    acc[i][j] = __builtin_amdgcn_mfma_f32_16x16x32_f16(
                        av[i], bv[j], acc[i][j], 0, 0, 0);
        }
    }

    #pragma unroll
    for (int i = 0; i < 4; ++i) {
        int rbase = bm + wr * 64 + i * 16 + quad * 4;
        #pragma unroll
        for (int j = 0; j < 4; ++j) {
            int cidx = bn + wc * 64 + j * 16 + l15;
            #pragma unroll
            for (int rr = 0; rr < 4; ++rr) {
                if (OUT_F16)
                    ((f16*)Cv)[(size_t)(rbase + rr) * N + cidx] = (f16)acc[i][j][rr];
                else
                    ((float*)Cv)[(size_t)(rbase + rr) * N + cidx] = acc[i][j][rr];
            }
        }
    }
}

// ---------------------------------------------------------------------------
// RMSNorm: fp32 strided in -> f16 compact out
// ---------------------------------------------------------------------------
__global__ __launch_bounds__(256) void rmsnorm_k(
    const float* __restrict__ in, int stride, int ncols,
    const float* __restrict__ gamma, f16* __restrict__ out)
{
    const int row = blockIdx.x;
    const float* x = in + (size_t)row * stride;

    float ss = 0.f;
    for (int c = threadIdx.x; c < ncols; c += 256) {
        float v = x[c];
        ss += v * v;
    }
    #pragma unroll
    for (int off = 32; off > 0; off >>= 1) ss += __shfl_down(ss, off);

    __shared__ float warp_s[4];
    __shared__ float scale_s;
    const int wid = threadIdx.x >> 6;
    if ((threadIdx.x & 63) == 0) warp_s[wid] = ss;
    __syncthreads();
    if (threadIdx.x == 0) {
        float t = warp_s[0] + warp_s[1] + warp_s[2] + warp_s[3];
        scale_s = rsqrtf(t / (float)ncols + EPS_RMS);
    }
    __syncthreads();
    const float sc = scale_s;
    for (int c = threadIdx.x; c < ncols; c += 256)
        out[(size_t)row * ncols + c] = (f16)(x[c] * gamma[c] * sc);
}

// ---------------------------------------------------------------------------
// RoPE
// ---------------------------------------------------------------------------
__device__ __forceinline__ float rope_one(int s, int d, float x, float other)
{
    const int j = d & 31;
    const float invf = expf(-0.28782313662425572f * (float)j); // 10000^(-j/32)
    const float ang = (float)s * invf;
    float sn, cs;
    sincosf(ang, &sn, &cs);
    float rot = (d < 32) ? -other : other;
    return x * cs + rot * sn;
}

// grid (S, 4), block 256: each wave rotates one head's q_pe
__global__ __launch_bounds__(256) void rope_q_k(f16* __restrict__ q)
{
    const int s = blockIdx.x;
    const int h = blockIdx.y * 4 + (threadIdx.x >> 6);
    const int d = threadIdx.x & 63;
    f16* base = q + (size_t)s * QB_N + h * HD_QK + DN;
    float x = (float)base[d];
    float other = (float)((d < 32) ? base[d + 32] : base[d - 32]);
    base[d] = (f16)rope_one(s, d, x, other);
}

// ---------------------------------------------------------------------------
// kfull[h][s][192] = concat(k_nope, rope(k_pe)); k_pe rotated inline from
// fused fp32.  MUST run before vt_k (vt aliases the fused region).
// ---------------------------------------------------------------------------
__global__ __launch_bounds__(256) void kfull_k(const f16* __restrict__ kv,
                                               const float* __restrict__ fused,
                                               f16* __restrict__ kfull)
{
    int n = blockIdx.x * 256 + threadIdx.x;   // < 16*2048*24
    int c8 = n % 24;
    int s = (n / 24) & 2047;
    int h = n / (24 * 2048);
    half8 v;
    if (c8 < 16) {
        v = *(const half8*)&kv[(size_t)s * KVB_N + h * 256 + c8 * 8];
    } else {
        const float* src = fused + (size_t)s * FPAD + (QL + KL);
        int dbase = (c8 - 16) * 8;
        #pragma unroll
        for (int j = 0; j < 8; ++j) {
            int d = dbase + j;
            float x = src[d];
            float other = src[(d < 32) ? d + 32 : d - 32];
            v[j] = (f16)rope_one(s, d, x, other);
        }
    }
    *(half8*)&kfull[((size_t)h * S_LEN + s) * HD_QK + c8 * 8] = v;
}

// ---------------------------------------------------------------------------
// vt[h][d][s] = kvbuf[s][h*256 + 128 + d]   (V transpose, 32x32 tiles)
// ---------------------------------------------------------------------------
__global__ __launch_bounds__(256) void vt_k(const f16* __restrict__ kv,
                                            f16* __restrict__ vt)
{
    __shared__ f16 t[32][33];
    const int s0 = blockIdx.x * 32, d0 = blockIdx.y * 32, h = blockIdx.z;
    const int tid = threadIdx.x;
    {
        const int c = tid & 31, rb = tid >> 5;
        #pragma unroll
        for (int i = 0; i < 4; ++i) {
            int r = rb + i * 8;  // s offset
            t[r][c] = kv[(size_t)(s0 + r) * KVB_N + h * 256 + 128 + d0 + c];
        }
    }
    __syncthreads();
    {
        const int d = tid >> 3, s4 = tid & 7;
        half4 v;
        v[0] = t[s4 * 4 + 0][d];
        v[1] = t[s4 * 4 + 1][d];
        v[2] = t[s4 * 4 + 2][d];
        v[3] = t[s4 * 4 + 3][d];
        *(half4*)&vt[((size_t)h * DV + d0 + d) * S_LEN + s0 + s4 * 4] = v;
    }
}

// ---------------------------------------------------------------------------
// MFMA flash attention (causal), split-K=2 (flash-decoding) + dbuf async
// staging.  grid (32, 16, 2): x->qb (balance-remapped), y->head, z->K-half.
// ---------------------------------------------------------------------------
__global__ __launch_bounds__(256) void attn_mfma_k(
    const f16* __restrict__ q,      // [S][3072]
    const f16* __restrict__ kfull,  // [NH][S][192]
    const f16* __restrict__ vt,     // [NH][128][S]
    f16* __restrict__ part_o,       // [2][S][2048]
    float* __restrict__ part_ml)    // [2][NH][S][2]
{
    __shared__ f16 sm[25088];

    const int tid = threadIdx.x;
    const int w = tid >> 6, lane = tid & 63;
    const int quad = lane >> 4, l15 = lane & 15;
    const int wbase = w * 64;
    const int h = blockIdx.y;
    const int z = blockIdx.z;
    const int qb = (blockIdx.y < 8) ? (int)blockIdx.x : 31 - (int)blockIdx.x;
    const int q0 = qb * 64;
    const int kt_begin = z ? (qb + 1) : 0;
    const int kt_end   = z ? (2 * qb + 2) : (qb + 1);
    const float scale2 = 0.10411755f;   // (1/sqrt(192)) * log2(e)

    const f16* kf_h = kfull + (size_t)h * S_LEN * HD_QK;
    const f16* vt_h = vt + (size_t)h * DV * S_LEN;

    // staging slot decodes (k0-independent)
    int koff[3];
    #pragma unroll
    for (int j = 0; j < 3; ++j) {
        int sig = j * 256 + tid;
        int r = sig / 24, cs = sig - r * 24;
        int ch = (cs & 24) | ((cs & 7) ^ (r & 7));
        koff[j] = r * HD_QK + ch * 8;
    }
    int voff[2];
    #pragma unroll
    for (int j = 0; j < 2; ++j) {
        int sig = j * 256 + tid;
        int rv = sig >> 2, c = (sig & 3) ^ ((rv >> 1) & 3);
        voff[j] = rv * S_LEN + c * 8;
    }

    // stage Q (64x192) -> sm+10240, and first K/V tile -> buf0, all async
    #pragma unroll
    for (int j = 0; j < 6; ++j) {
        int sig = j * 256 + tid;
        int r = sig / 24, cs = sig - r * 24;
        int ch = (cs & 24) | ((cs & 7) ^ (r & 7));
        async16(q + (size_t)(q0 + r) * QB_N + h * HD_QK + ch * 8,
                sm + 10240 + (j * 256 + wbase) * 8);
    }
    {
        const f16* kg = kf_h + (size_t)kt_begin * 32 * HD_QK;
        const f16* vg = vt_h + kt_begin * 32;
        #pragma unroll
        for (int j = 0; j < 3; ++j) async16(kg + koff[j], sm + (j * 256 + wbase) * 8);
        #pragma unroll
        for (int j = 0; j < 2; ++j) async16(vg + voff[j], sm + 6144 + (j * 256 + wbase) * 8);
    }
    __syncthreads();

    // Q fragments
    half8 qf[6];
    const int qrow = w * 16 + l15;
    #pragma unroll
    for (int kd = 0; kd < 6; ++kd) {
        int c = kd * 4 + quad;
        int cs = (c & 24) | ((c & 7) ^ (qrow & 7));
        qf[kd] = *(const half8*)&sm[10240 + (qrow * 24 + cs) * 8];
    }

    half8 ones_h;
    #pragma unroll
    for (int j = 0; j < 8; ++j) ones_h[j] = (f16)1.0f;

    floatx4 o[8] = {};
    floatx4 o_l = {};
    float m_i[4];
    #pragma unroll
    for (int r = 0; r < 4; ++r) m_i[r] = -1e30f;

    const int qrow_min = q0 + w * 16;
    f16* Pw = sm + 22528 + w * 640;

    for (int kt = kt_begin; kt < kt_end; ++kt) {
        const int cur = (kt - kt_begin) & 1;
        __syncthreads();          // buf[1-cur] free; buf[cur] loads drained
        if (kt + 1 < kt_end) {    // prefetch next tile into buf[1-cur]
            const int nxt = 1 - cur;
            const int k0n = (kt + 1) * 32;
            f16* kb = sm + (nxt ? 10240 : 0);
            f16* vb = sm + (nxt ? 16384 : 6144);
            const f16* kg = kf_h + (size_t)k0n * HD_QK;
            const f16* vg = vt_h + k0n;
            #pragma unroll
            for (int j = 0; j < 3; ++j) async16(kg + koff[j], kb + (j * 256 + wbase) * 8);
            #pragma unroll
            for (int j = 0; j < 2; ++j) async16(vg + voff[j], vb + (j * 256 + wbase) * 8);
        }
        const int k0 = kt * 32;
        if (k0 > qrow_min + 15) continue;   // causally done for this wave

        const f16* kb = sm + (cur ? 10240 : 0);
        const f16* vb = sm + (cur ? 16384 : 6144);

        // QK^T (16 x 32)
        floatx4 s0 = {}, s1 = {};
        #pragma unroll
        for (int kd = 0; kd < 6; ++kd) {
            int c = kd * 4 + quad;
            int cs = (c & 24) | ((c & 7) ^ (l15 & 7));
            half8 b0 = *(const half8*)&kb[(l15 * 24 + cs) * 8];
            half8 b1 = *(const half8*)&kb[((l15 + 16) * 24 + cs) * 8];
            s0 = __builtin_amdgcn_mfma_f32_16x16x32_f16(qf[kd], b0, s0, 0, 0, 0);
            s1 = __builtin_amdgcn_mfma_f32_16x16x32_f16(qf[kd], b1, s1, 0, 0, 0);
        }

        // mask + scale (log2 domain) + row-max (16-lane shuffles)
        const bool nm = (k0 + 31 > qrow_min);
        float mt[4];
        #pragma unroll
        for (int r = 0; r < 4; ++r) {
            float v0 = s0[r] * scale2, v1 = s1[r] * scale2;
            if (nm) {
                int row = qrow_min + quad * 4 + r;
                if (k0 + l15 > row)      v0 = -1e30f;
                if (k0 + 16 + l15 > row) v1 = -1e30f;
            }
            s0[r] = v0; s1[r] = v1;
            mt[r] = fmaxf(v0, v1);
        }
        #pragma unroll
        for (int r = 0; r < 4; ++r) {
            mt[r] = fmaxf(mt[r], __shfl_xor(mt[r], 1));
            mt[r] = fmaxf(mt[r], __shfl_xor(mt[r], 2));
            mt[r] = fmaxf(mt[r], __shfl_xor(mt[r], 4));
            mt[r] = fmaxf(mt[r], __shfl_xor(mt[r], 8));
        }
        float alpha[4];
        #pragma unroll
        for (int r = 0; r < 4; ++r) {
            float mn = fmaxf(m_i[r], mt[r]);
            alpha[r] = __builtin_exp2f(m_i[r] - mn);
            m_i[r] = mn;
            s0[r] = __builtin_exp2f(s0[r] - mn);
            s1[r] = __builtin_exp2f(s1[r] - mn);
        }

        // P: C-layout -> wave-private LDS
        #pragma unroll
        for (int r = 0; r < 4; ++r) {
            Pw[(quad * 4 + r) * 40 + l15]      = (f16)s0[r];
            Pw[(quad * 4 + r) * 40 + 16 + l15] = (f16)s1[r];
        }

        // rescale O and l
        #pragma unroll
        for (int nb = 0; nb < 8; ++nb)
            #pragma unroll
            for (int r = 0; r < 4; ++r) o[nb][r] *= alpha[r];
        #pragma unroll
        for (int r = 0; r < 4; ++r) o_l[r] *= alpha[r];

        // PV (+ row-sum via ones-B MFMA; no cross-lane ops)
        half8 pa = *(const half8*)&Pw[l15 * 40 + quad * 8];
        o_l = __builtin_amdgcn_mfma_f32_16x16x32_f16(pa, ones_h, o_l, 0, 0, 0);
        #pragma unroll
        for (int nb = 0; nb < 8; ++nb) {
            int rv = nb * 16 + l15;
            int sig = rv * 4 + (quad ^ ((l15 >> 1) & 3));
            half8 vv = *(const half8*)&vb[sig * 8];
            o[nb] = __builtin_amdgcn_mfma_f32_16x16x32_f16(pa, vv, o[nb], 0, 0, 0);
        }
    }

    float inv[4];
    #pragma unroll
    for (int r = 0; r < 4; ++r) inv[r] = (o_l[r] > 0.f) ? 1.f / o_l[r] : 0.f;

    f16* po = part_o + (size_t)z * S_LEN * 2048;
    #pragma unroll
    for (int nb = 0; nb < 8; ++nb) {
        #pragma unroll
        for (int r = 0; r < 4; ++r) {
            int row = q0 + w * 16 + quad * 4 + r;
            po[(size_t)row * (NH * DV) + h * DV + nb * 16 + l15] =
                (f16)(o[nb][r] * inv[r]);
        }
    }
    if (l15 == 0) {
        #pragma unroll
        for (int r = 0; r < 4; ++r) {
            int row = q0 + w * 16 + quad * 4 + r;
            float* ml = part_ml + (((size_t)z * NH + h) * S_LEN + row) * 2;
            ml[0] = m_i[r];
            ml[1] = o_l[r];
        }
    }
}

// ---------------------------------------------------------------------------
// Combine the two split-K halves:  O = (w0*O0n + w1*O1n),  wz = lz*2^(mz-M).
// ---------------------------------------------------------------------------
__global__ __launch_bounds__(256) void attn_comb_k(
    const f16* __restrict__ part_o, const float* __restrict__ part_ml,
    f16* __restrict__ attnb)
{
    int g = blockIdx.x * 256 + threadIdx.x;       // < 2048*2048/8
    int h = (g >> 4) & 15;
    int s = g >> 8;
    const float* ml0 = part_ml + ((size_t)h * S_LEN + s) * 2;
    const float* ml1 = part_ml + (((size_t)NH + h) * S_LEN + s) * 2;
    float m0 = ml0[0], l0 = ml0[1];
    float m1 = ml1[0], l1 = ml1[1];
    float M = fmaxf(m0, m1);
    float w0 = l0 * __builtin_exp2f(m0 - M);
    float w1 = l1 * __builtin_exp2f(m1 - M);
    float inv = 1.f / (w0 + w1);
    w0 *= inv; w1 *= inv;
    half8 p0 = *(const half8*)&part_o[(size_t)g * 8];
    half8 p1 = *(const half8*)&part_o[(size_t)(524288 + g) * 8];
    half8 r;
    #pragma unroll
    for (int j = 0; j < 8; ++j)
        r[j] = (f16)(w0 * (float)p0[j] + w1 * (float)p1[j]);
    *(half8*)&attnb[(size_t)g * 8] = r;
}

// ---------------------------------------------------------------------------
// Launch
// ---------------------------------------------------------------------------
extern "C" void kernel_launch(void* const* d_in, const int* in_sizes, int n_in,
                              void* d_out, int out_size, void* d_ws, size_t ws_size,
                              hipStream_t stream)
{
    const float* hidden   = (const float*)d_in[0];
    const float* w_kv_a   = (const float*)d_in[1];
    const float* q_gamma  = (const float*)d_in[2];
    const float* w_qb     = (const float*)d_in[3];
    const float* kv_gamma = (const float*)d_in[4];
    const float* w_kvb    = (const float*)d_in[5];
    const float* w_o      = (const float*)d_in[6];
    float* out = (float*)d_out;

    char* p = (char*)d_ws;
    f16* hid_h   = (f16*)p;  p += (size_t)2048 * 2048 * 2;
    f16* wkva_t  = (f16*)p;  p += (size_t)2176 * 2048 * 2;
    f16* wqb_t   = (f16*)p;  p += (size_t)3072 * 1536 * 2;
    f16* wkvb_t  = (f16*)p;  p += (size_t)4096 * 512 * 2;
    f16* wo_t    = (f16*)p;  p += (size_t)2048 * 2048 * 2;
    float* fused = (float*)p; p += (size_t)2048 * FPAD * 4;
    f16* q_n     = (f16*)p;  p += (size_t)2048 * QL * 2;
    f16* qbuf    = (f16*)p;  p += (size_t)2048 * QB_N * 2;
    f16* kv_n    = (f16*)p;  p += (size_t)2048 * KL * 2;
    f16* kvbuf   = (f16*)p;  p += (size_t)2048 * KVB_N * 2;
    f16* attnb   = (f16*)p;  p += (size_t)2048 * 2048 * 2;
    f16* part_o  = (f16*)p;  p += (size_t)2 * 2048 * 2048 * 2;
    float* part_ml = (float*)p; p += (size_t)2 * NH * 2048 * 2 * 4;

    // aliases onto dead regions:
    //   kfull [16][2048][192] f16 (12.6 MB) <- hid_h+wkva_t (dead after gemm1)
    //   vt    [16][128][2048] f16 ( 8.4 MB) <- fused (dead after kfull_k)
    f16* kfull = hid_h;
    f16* vt    = (f16*)fused;

    dim3 blk(256);

    cvt_f16_k<<<(2048 * 2048 / 4 + 255) / 256, blk, 0, stream>>>(hidden, hid_h, 2048 * 2048 / 4);
    tconv_k<<<dim3(2176 / 32, 2048 / 32), blk, 0, stream>>>(w_kv_a, wkva_t, 2048, FUSED_N);
    tconv_k<<<dim3(3072 / 32, 1536 / 32), blk, 0, stream>>>(w_qb,   wqb_t,  1536, QB_N);
    tconv_k<<<dim3(4096 / 32,  512 / 32), blk, 0, stream>>>(w_kvb,  wkvb_t,  512, KVB_N);
    tconv_k<<<dim3(2048 / 32, 2048 / 32), blk, 0, stream>>>(w_o,    wo_t,   2048, 2048);

    gemm_mfma<0><<<dim3(FPAD / 128, 2048 / 128), blk, 0, stream>>>(
        hid_h, wkva_t, fused, 2048, FPAD, 2048);

    rmsnorm_k<<<2048, blk, 0, stream>>>(fused, FPAD, QL, q_gamma, q_n);
    rmsnorm_k<<<2048, blk, 0, stream>>>(fused + QL, FPAD, KL, kv_gamma, kv_n);

    gemm_mfma<1><<<dim3(QB_N / 128, 2048 / 128), blk, 0, stream>>>(
        q_n, wqb_t, qbuf, 2048, QB_N, QL);
    gemm_mfma<1><<<dim3(KVB_N / 128, 2048 / 128), blk, 0, stream>>>(
        kv_n, wkvb_t, kvbuf, 2048, KVB_N, KL);

    rope_q_k<<<dim3(2048, 4), blk, 0, stream>>>(qbuf);

    // kfull (reads fused for k_pe rope) BEFORE vt_k (vt overwrites fused)
    kfull_k<<<16 * 2048 * 24 / 256, blk, 0, stream>>>(kvbuf, fused, kfull);
    vt_k<<<dim3(2048 / 32, 128 / 32, NH), blk, 0, stream>>>(kvbuf, vt);

    attn_mfma_k<<<dim3(32, NH, 2), blk, 0, stream>>>(qbuf, kfull, vt, part_o, part_ml);
    attn_comb_k<<<2048, blk, 0, stream>>>(part_o, part_ml, attnb);

    gemm_mfma<0><<<dim3(2048 / 128, 2048 / 128), blk, 0, stream>>>(
        attnb, wo_t, out, 2048, 2048, 2048);
}

// Round 8
// 328.389 us; speedup vs baseline: 12.0210x; 1.0860x over previous
//
#include <hip/hip_runtime.h>
#include <math.h>

#define S_LEN 2048
#define NH 16
#define DN 128
#define DR 64
#define DV 128
#define QL 1536
#define KL 512
#define FUSED_N 2112
#define FPAD 2176            // fused padded to 17*128
#define QB_N 3072
#define KVB_N 4096
#define HD_QK 192
#define EPS_RMS 1e-6f

typedef _Float16 f16;
typedef _Float16 half8 __attribute__((ext_vector_type(8)));
typedef _Float16 half4 __attribute__((ext_vector_type(4)));
typedef float floatx4 __attribute__((ext_vector_type(4)));

__device__ __forceinline__ void async16(const f16* gp, f16* lp)
{
    __builtin_amdgcn_global_load_lds(
        (const __attribute__((address_space(1))) void*)gp,
        (__attribute__((address_space(3))) void*)lp, 16, 0, 0);
}

// ---------------------------------------------------------------------------
// GEMM core: C[128 x 64] tile of A[M,K] @ Bt[N,K]^T.  BK=64, dbuf async.
// sm layout per buf (f16): A [0,8192) = 128x64, B [8192,12288) = 64x64.
// 4 waves in 2x2: wave = 64 rows x 32 cols = 4x2 MFMAs of 16x16x32.
// ---------------------------------------------------------------------------
template <int OUT_F16>
__device__ __forceinline__ void gemm_core(
    const f16* __restrict__ A, const f16* __restrict__ Bt,
    void* __restrict__ Cv, int N, int K, int bm, int bn, f16* sm)
{
    const int tid = threadIdx.x;
    const int wv = tid >> 6, lane = tid & 63;
    const int quad = lane >> 4, l15 = lane & 15;
    const int wr = wv >> 1, wc = wv & 1;
    const int srow = lane >> 3, sc = lane & 7;

    size_t aoff[4]; int lda[4];
    #pragma unroll
    for (int t = 0; t < 4; ++t) {
        int rl = wv * 32 + t * 8 + srow;
        int ch = sc ^ (rl & 7);
        aoff[t] = (size_t)(bm + rl) * K + ch * 8;
        lda[t] = (wv * 32 + t * 8) * 64;
    }
    size_t boff[2]; int ldb[2];
    #pragma unroll
    for (int t = 0; t < 2; ++t) {
        int rl = wv * 16 + t * 8 + srow;
        int ch = sc ^ (rl & 7);
        boff[t] = (size_t)(bn + rl) * K + ch * 8;
        ldb[t] = 8192 + (wv * 16 + t * 8) * 64;
    }

    #pragma unroll
    for (int t = 0; t < 4; ++t) async16(A  + aoff[t], &sm[lda[t]]);
    #pragma unroll
    for (int t = 0; t < 2; ++t) async16(Bt + boff[t], &sm[ldb[t]]);

    floatx4 acc[4][2] = {};
    const int nsteps = K >> 6;

    for (int step = 0; step < nsteps; ++step) {
        const int cur = step & 1;
        __syncthreads();
        if (step + 1 < nsteps) {
            const int k0n = (step + 1) << 6;
            f16* nb = sm + (1 - cur) * 12288;
            #pragma unroll
            for (int t = 0; t < 4; ++t) async16(A  + aoff[t] + k0n, nb + lda[t]);
            #pragma unroll
            for (int t = 0; t < 2; ++t) async16(Bt + boff[t] + k0n, nb + ldb[t]);
        }
        const f16* As = sm + cur * 12288;
        const f16* Bs = As + 8192;

        #pragma unroll
        for (int ks = 0; ks < 2; ++ks) {
            half8 av[4], bv[2];
            #pragma unroll
            for (int i = 0; i < 4; ++i) {
                int m = wr * 64 + i * 16 + l15;
                av[i] = *(const half8*)&As[m * 64 + ((ks * 4 + quad) ^ (m & 7)) * 8];
            }
            #pragma unroll
            for (int j = 0; j < 2; ++j) {
                int n = wc * 32 + j * 16 + l15;
                bv[j] = *(const half8*)&Bs[n * 64 + ((ks * 4 + quad) ^ (n & 7)) * 8];
            }
            #pragma unroll
            for (int i = 0; i < 4; ++i)
                #pragma unroll
                for (int j = 0; j < 2; ++j)
                    acc[i][j] = __builtin_amdgcn_mfma_f32_16x16x32_f16(
                        av[i], bv[j], acc[i][j], 0, 0, 0);
        }
    }

    #pragma unroll
    for (int i = 0; i < 4; ++i) {
        int rbase = bm + wr * 64 + i * 16 + quad * 4;
        #pragma unroll
        for (int j = 0; j < 2; ++j) {
            int cidx = bn + wc * 32 + j * 16 + l15;
            #pragma unroll
            for (int rr = 0; rr < 4; ++rr) {
                if (OUT_F16)
                    ((f16*)Cv)[(size_t)(rbase + rr) * N + cidx] = (f16)acc[i][j][rr];
                else
                    ((float*)Cv)[(size_t)(rbase + rr) * N + cidx] = acc[i][j][rr];
            }
        }
    }
}

template <int OUT_F16>
__global__ __launch_bounds__(256) void gemm_mfma(
    const f16* __restrict__ A, const f16* __restrict__ Bt,
    void* __restrict__ Cv, int N, int K)
{
    __shared__ f16 sm[2 * 12288];
    gemm_core<OUT_F16>(A, Bt, Cv, N, K, blockIdx.y * 128, blockIdx.x * 64, sm);
}

// Fused independent GEMMs: x<48 -> qbuf = q_n @ wqb^T ; else kvbuf = kv_n @ wkvb^T
__global__ __launch_bounds__(256) void gemm_dual(
    const f16* __restrict__ A1, const f16* __restrict__ B1, f16* __restrict__ C1,
    const f16* __restrict__ A2, const f16* __restrict__ B2, f16* __restrict__ C2)
{
    __shared__ f16 sm[2 * 12288];
    int bx = blockIdx.x;
    if (bx < 48)
        gemm_core<1>(A1, B1, C1, QB_N, QL, blockIdx.y * 128, bx * 64, sm);
    else
        gemm_core<1>(A2, B2, C2, KVB_N, KL, blockIdx.y * 128, (bx - 48) * 64, sm);
}

// ---------------------------------------------------------------------------
// Fused prep: cvt(hidden->f16) + 4x transpose-convert weights.
// Linear block ranges:
//   [0,4096)                cvt
//   [4096,8448)             w_kv_a  (68 x 64)   K=2048 N=2112 (pad 2176)
//   [8448,13056)            w_qb    (96 x 48)   K=1536 N=3072
//   [13056,15104)           w_kvb   (128 x 16)  K=512  N=4096
//   [15104,19200)           w_o     (64 x 64)   K=2048 N=2048
// ---------------------------------------------------------------------------
__device__ __forceinline__ void tconv_core(
    const float* __restrict__ in, f16* __restrict__ out,
    int K, int N, int n0, int k0, float t[32][33])
{
    const int c = threadIdx.x & 31, r8 = threadIdx.x >> 5;
    #pragma unroll
    for (int i = 0; i < 4; ++i) {
        int r = r8 + i * 8;
        int gc = n0 + c;
        t[r][c] = (gc < N) ? in[(size_t)(k0 + r) * N + gc] : 0.f;
    }
    __syncthreads();
    #pragma unroll
    for (int i = 0; i < 4; ++i) {
        int r = r8 + i * 8;
        out[(size_t)(n0 + r) * K + k0 + c] = (f16)t[c][r];
    }
}

__global__ __launch_bounds__(256) void prep_k(
    const float* __restrict__ hidden, f16* __restrict__ hid_h,
    const float* __restrict__ w_kv_a, f16* __restrict__ wkva_t,
    const float* __restrict__ w_qb,   f16* __restrict__ wqb_t,
    const float* __restrict__ w_kvb,  f16* __restrict__ wkvb_t,
    const float* __restrict__ w_o,    f16* __restrict__ wo_t)
{
    __shared__ float t[32][33];
    int b = blockIdx.x;
    if (b < 4096) {
        int i = b * 256 + threadIdx.x;
        float4 v = ((const float4*)hidden)[i];
        half4 h;
        h[0] = (f16)v.x; h[1] = (f16)v.y; h[2] = (f16)v.z; h[3] = (f16)v.w;
        ((half4*)hid_h)[i] = h;
    } else if (b < 8448) {
        int r = b - 4096;
        tconv_core(w_kv_a, wkva_t, 2048, FUSED_N, (r % 68) * 32, (r / 68) * 32, t);
    } else if (b < 13056) {
        int r = b - 8448;
        tconv_core(w_qb, wqb_t, QL, QB_N, (r % 96) * 32, (r / 96) * 32, t);
    } else if (b < 15104) {
        int r = b - 13056;
        tconv_core(w_kvb, wkvb_t, KL, KVB_N, (r % 128) * 32, (r / 128) * 32, t);
    } else {
        int r = b - 15104;
        tconv_core(w_o, wo_t, 2048, 2048, (r % 64) * 32, (r / 64) * 32, t);
    }
}

// ---------------------------------------------------------------------------
// Fused RMSNorm (rows 0..2047 -> q_n, 2048..4095 -> kv_n)
// ---------------------------------------------------------------------------
__global__ __launch_bounds__(256) void rmsnorm_k(
    const float* __restrict__ fused, const float* __restrict__ q_gamma,
    const float* __restrict__ kv_gamma, f16* __restrict__ q_n,
    f16* __restrict__ kv_n)
{
    const int b = blockIdx.x;
    const bool isq = b < 2048;
    const int row = isq ? b : b - 2048;
    const int ncols = isq ? QL : KL;
    const float* x = fused + (size_t)row * FPAD + (isq ? 0 : QL);
    const float* gamma = isq ? q_gamma : kv_gamma;
    f16* out = isq ? q_n : kv_n;

    float ss = 0.f;
    for (int c = threadIdx.x; c < ncols; c += 256) {
        float v = x[c];
        ss += v * v;
    }
    #pragma unroll
    for (int off = 32; off > 0; off >>= 1) ss += __shfl_down(ss, off);

    __shared__ float warp_s[4];
    __shared__ float scale_s;
    const int wid = threadIdx.x >> 6;
    if ((threadIdx.x & 63) == 0) warp_s[wid] = ss;
    __syncthreads();
    if (threadIdx.x == 0) {
        float tt = warp_s[0] + warp_s[1] + warp_s[2] + warp_s[3];
        scale_s = rsqrtf(tt / (float)ncols + EPS_RMS);
    }
    __syncthreads();
    const float sc = scale_s;
    for (int c = threadIdx.x; c < ncols; c += 256)
        out[(size_t)row * ncols + c] = (f16)(x[c] * gamma[c] * sc);
}

// ---------------------------------------------------------------------------
// RoPE helper
// ---------------------------------------------------------------------------
__device__ __forceinline__ float rope_one(int s, int d, float x, float other)
{
    const int j = d & 31;
    const float invf = expf(-0.28782313662425572f * (float)j); // 10000^(-j/32)
    const float ang = (float)s * invf;
    float sn, cs;
    sincosf(ang, &sn, &cs);
    float rot = (d < 32) ? -other : other;
    return x * cs + rot * sn;
}

// ---------------------------------------------------------------------------
// Fused post: rope_q (q_pe in-place) + kfull (concat + k_pe rope) + vt.
// vt aliases wkva_t (dead), kfull aliases hid_h (dead) -> no RAW hazard with
// fused (kfull reads fused fp32; vt does NOT touch it).
// Ranges: [0,8192) rope_q ; [8192,11264) kfull ; [11264,15360) vt.
// ---------------------------------------------------------------------------
__global__ __launch_bounds__(256) void post_k(
    f16* __restrict__ q, const f16* __restrict__ kv,
    const float* __restrict__ fused, f16* __restrict__ kfull,
    f16* __restrict__ vt)
{
    __shared__ f16 t[32][33];
    int b = blockIdx.x;
    if (b < 8192) {
        const int s = b & 2047;
        const int h = (b >> 11) * 4 + (threadIdx.x >> 6);
        const int d = threadIdx.x & 63;
        f16* base = q + (size_t)s * QB_N + h * HD_QK + DN;
        float x = (float)base[d];
        float other = (float)((d < 32) ? base[d + 32] : base[d - 32]);
        base[d] = (f16)rope_one(s, d, x, other);
    } else if (b < 11264) {
        int n = (b - 8192) * 256 + threadIdx.x;   // < 16*2048*24
        int c8 = n % 24;
        int s = (n / 24) & 2047;
        int h = n / (24 * 2048);
        half8 v;
        if (c8 < 16) {
            v = *(const half8*)&kv[(size_t)s * KVB_N + h * 256 + c8 * 8];
        } else {
            const float* src = fused + (size_t)s * FPAD + (QL + KL);
            int dbase = (c8 - 16) * 8;
            #pragma unroll
            for (int j = 0; j < 8; ++j) {
                int d = dbase + j;
                float x = src[d];
                float other = src[(d < 32) ? d + 32 : d - 32];
                v[j] = (f16)rope_one(s, d, x, other);
            }
        }
        *(half8*)&kfull[((size_t)h * S_LEN + s) * HD_QK + c8 * 8] = v;
    } else {
        int r = b - 11264;
        const int s0 = (r & 63) * 32, d0 = ((r >> 6) & 3) * 32, h = r >> 8;
        const int tid = threadIdx.x;
        {
            const int c = tid & 31, rb = tid >> 5;
            #pragma unroll
            for (int i = 0; i < 4; ++i) {
                int rr = rb + i * 8;
                t[rr][c] = kv[(size_t)(s0 + rr) * KVB_N + h * 256 + 128 + d0 + c];
            }
        }
        __syncthreads();
        {
            const int d = tid >> 3, s4 = tid & 7;
            half4 v;
            v[0] = t[s4 * 4 + 0][d];
            v[1] = t[s4 * 4 + 1][d];
            v[2] = t[s4 * 4 + 2][d];
            v[3] = t[s4 * 4 + 3][d];
            *(half4*)&vt[((size_t)h * DV + d0 + d) * S_LEN + s0 + s4 * 4] = v;
        }
    }
}

// ---------------------------------------------------------------------------
// MFMA flash attention (causal), split-K=2 + dbuf async staging (unchanged).
// ---------------------------------------------------------------------------
__global__ __launch_bounds__(256) void attn_mfma_k(
    const f16* __restrict__ q,      // [S][3072]
    const f16* __restrict__ kfull,  // [NH][S][192]
    const f16* __restrict__ vt,     // [NH][128][S]
    f16* __restrict__ part_o,       // [2][S][2048]
    float* __restrict__ part_ml)    // [2][NH][S][2]
{
    __shared__ f16 sm[25088];

    const int tid = threadIdx.x;
    const int w = tid >> 6, lane = tid & 63;
    const int quad = lane >> 4, l15 = lane & 15;
    const int wbase = w * 64;
    const int h = blockIdx.y;
    const int z = blockIdx.z;
    const int qb = (blockIdx.y < 8) ? (int)blockIdx.x : 31 - (int)blockIdx.x;
    const int q0 = qb * 64;
    const int kt_begin = z ? (qb + 1) : 0;
    const int kt_end   = z ? (2 * qb + 2) : (qb + 1);
    const float scale2 = 0.10411755f;   // (1/sqrt(192)) * log2(e)

    const f16* kf_h = kfull + (size_t)h * S_LEN * HD_QK;
    const f16* vt_h = vt + (size_t)h * DV * S_LEN;

    int koff[3];
    #pragma unroll
    for (int j = 0; j < 3; ++j) {
        int sig = j * 256 + tid;
        int r = sig / 24, cs = sig - r * 24;
        int ch = (cs & 24) | ((cs & 7) ^ (r & 7));
        koff[j] = r * HD_QK + ch * 8;
    }
    int voff[2];
    #pragma unroll
    for (int j = 0; j < 2; ++j) {
        int sig = j * 256 + tid;
        int rv = sig >> 2, c = (sig & 3) ^ ((rv >> 1) & 3);
        voff[j] = rv * S_LEN + c * 8;
    }

    #pragma unroll
    for (int j = 0; j < 6; ++j) {
        int sig = j * 256 + tid;
        int r = sig / 24, cs = sig - r * 24;
        int ch = (cs & 24) | ((cs & 7) ^ (r & 7));
        async16(q + (size_t)(q0 + r) * QB_N + h * HD_QK + ch * 8,
                sm + 10240 + (j * 256 + wbase) * 8);
    }
    {
        const f16* kg = kf_h + (size_t)kt_begin * 32 * HD_QK;
        const f16* vg = vt_h + kt_begin * 32;
        #pragma unroll
        for (int j = 0; j < 3; ++j) async16(kg + koff[j], sm + (j * 256 + wbase) * 8);
        #pragma unroll
        for (int j = 0; j < 2; ++j) async16(vg + voff[j], sm + 6144 + (j * 256 + wbase) * 8);
    }
    __syncthreads();

    half8 qf[6];
    const int qrow = w * 16 + l15;
    #pragma unroll
    for (int kd = 0; kd < 6; ++kd) {
        int c = kd * 4 + quad;
        int cs = (c & 24) | ((c & 7) ^ (qrow & 7));
        qf[kd] = *(const half8*)&sm[10240 + (qrow * 24 + cs) * 8];
    }

    half8 ones_h;
    #pragma unroll
    for (int j = 0; j < 8; ++j) ones_h[j] = (f16)1.0f;

    floatx4 o[8] = {};
    floatx4 o_l = {};
    float m_i[4];
    #pragma unroll
    for (int r = 0; r < 4; ++r) m_i[r] = -1e30f;

    const int qrow_min = q0 + w * 16;
    f16* Pw = sm + 22528 + w * 640;

    for (int kt = kt_begin; kt < kt_end; ++kt) {
        const int cur = (kt - kt_begin) & 1;
        __syncthreads();
        if (kt + 1 < kt_end) {
            const int nxt = 1 - cur;
            const int k0n = (kt + 1) * 32;
            f16* kb = sm + (nxt ? 10240 : 0);
            f16* vb = sm + (nxt ? 16384 : 6144);
            const f16* kg = kf_h + (size_t)k0n * HD_QK;
            const f16* vg = vt_h + k0n;
            #pragma unroll
            for (int j = 0; j < 3; ++j) async16(kg + koff[j], kb + (j * 256 + wbase) * 8);
            #pragma unroll
            for (int j = 0; j < 2; ++j) async16(vg + voff[j], vb + (j * 256 + wbase) * 8);
        }
        const int k0 = kt * 32;
        if (k0 > qrow_min + 15) continue;

        const f16* kb = sm + (cur ? 10240 : 0);
        const f16* vb = sm + (cur ? 16384 : 6144);

        floatx4 s0 = {}, s1 = {};
        #pragma unroll
        for (int kd = 0; kd < 6; ++kd) {
            int c = kd * 4 + quad;
            int cs = (c & 24) | ((c & 7) ^ (l15 & 7));
            half8 b0 = *(const half8*)&kb[(l15 * 24 + cs) * 8];
            half8 b1 = *(const half8*)&kb[((l15 + 16) * 24 + cs) * 8];
            s0 = __builtin_amdgcn_mfma_f32_16x16x32_f16(qf[kd], b0, s0, 0, 0, 0);
            s1 = __builtin_amdgcn_mfma_f32_16x16x32_f16(qf[kd], b1, s1, 0, 0, 0);
        }

        const bool nm = (k0 + 31 > qrow_min);
        float mt[4];
        #pragma unroll
        for (int r = 0; r < 4; ++r) {
            float v0 = s0[r] * scale2, v1 = s1[r] * scale2;
            if (nm) {
                int row = qrow_min + quad * 4 + r;
                if (k0 + l15 > row)      v0 = -1e30f;
                if (k0 + 16 + l15 > row) v1 = -1e30f;
            }
            s0[r] = v0; s1[r] = v1;
            mt[r] = fmaxf(v0, v1);
        }
        #pragma unroll
        for (int r = 0; r < 4; ++r) {
            mt[r] = fmaxf(mt[r], __shfl_xor(mt[r], 1));
            mt[r] = fmaxf(mt[r], __shfl_xor(mt[r], 2));
            mt[r] = fmaxf(mt[r], __shfl_xor(mt[r], 4));
            mt[r] = fmaxf(mt[r], __shfl_xor(mt[r], 8));
        }
        float alpha[4];
        #pragma unroll
        for (int r = 0; r < 4; ++r) {
            float mn = fmaxf(m_i[r], mt[r]);
            alpha[r] = __builtin_exp2f(m_i[r] - mn);
            m_i[r] = mn;
            s0[r] = __builtin_exp2f(s0[r] - mn);
            s1[r] = __builtin_exp2f(s1[r] - mn);
        }

        #pragma unroll
        for (int r = 0; r < 4; ++r) {
            Pw[(quad * 4 + r) * 40 + l15]      = (f16)s0[r];
            Pw[(quad * 4 + r) * 40 + 16 + l15] = (f16)s1[r];
        }

        #pragma unroll
        for (int nb = 0; nb < 8; ++nb)
            #pragma unroll
            for (int r = 0; r < 4; ++r) o[nb][r] *= alpha[r];
        #pragma unroll
        for (int r = 0; r < 4; ++r) o_l[r] *= alpha[r];

        half8 pa = *(const half8*)&Pw[l15 * 40 + quad * 8];
        o_l = __builtin_amdgcn_mfma_f32_16x16x32_f16(pa, ones_h, o_l, 0, 0, 0);
        #pragma unroll
        for (int nb = 0; nb < 8; ++nb) {
            int rv = nb * 16 + l15;
            int sig = rv * 4 + (quad ^ ((l15 >> 1) & 3));
            half8 vv = *(const half8*)&vb[sig * 8];
            o[nb] = __builtin_amdgcn_mfma_f32_16x16x32_f16(pa, vv, o[nb], 0, 0, 0);
        }
    }

    float inv[4];
    #pragma unroll
    for (int r = 0; r < 4; ++r) inv[r] = (o_l[r] > 0.f) ? 1.f / o_l[r] : 0.f;

    f16* po = part_o + (size_t)z * S_LEN * 2048;
    #pragma unroll
    for (int nb = 0; nb < 8; ++nb) {
        #pragma unroll
        for (int r = 0; r < 4; ++r) {
            int row = q0 + w * 16 + quad * 4 + r;
            po[(size_t)row * (NH * DV) + h * DV + nb * 16 + l15] =
                (f16)(o[nb][r] * inv[r]);
        }
    }
    if (l15 == 0) {
        #pragma unroll
        for (int r = 0; r < 4; ++r) {
            int row = q0 + w * 16 + quad * 4 + r;
            float* ml = part_ml + (((size_t)z * NH + h) * S_LEN + row) * 2;
            ml[0] = m_i[r];
            ml[1] = o_l[r];
        }
    }
}

// ---------------------------------------------------------------------------
// Combine the two split-K halves.
// ---------------------------------------------------------------------------
__global__ __launch_bounds__(256) void attn_comb_k(
    const f16* __restrict__ part_o, const float* __restrict__ part_ml,
    f16* __restrict__ attnb)
{
    int g = blockIdx.x * 256 + threadIdx.x;       // < 2048*2048/8
    int h = (g >> 4) & 15;
    int s = g >> 8;
    const float* ml0 = part_ml + ((size_t)h * S_LEN + s) * 2;
    const float* ml1 = part_ml + (((size_t)NH + h) * S_LEN + s) * 2;
    float m0 = ml0[0], l0 = ml0[1];
    float m1 = ml1[0], l1 = ml1[1];
    float M = fmaxf(m0, m1);
    float w0 = l0 * __builtin_exp2f(m0 - M);
    float w1 = l1 * __builtin_exp2f(m1 - M);
    float inv = 1.f / (w0 + w1);
    w0 *= inv; w1 *= inv;
    half8 p0 = *(const half8*)&part_o[(size_t)g * 8];
    half8 p1 = *(const half8*)&part_o[(size_t)(524288 + g) * 8];
    half8 r;
    #pragma unroll
    for (int j = 0; j < 8; ++j)
        r[j] = (f16)(w0 * (float)p0[j] + w1 * (float)p1[j]);
    *(half8*)&attnb[(size_t)g * 8] = r;
}

// ---------------------------------------------------------------------------
// Launch
// ---------------------------------------------------------------------------
extern "C" void kernel_launch(void* const* d_in, const int* in_sizes, int n_in,
                              void* d_out, int out_size, void* d_ws, size_t ws_size,
                              hipStream_t stream)
{
    const float* hidden   = (const float*)d_in[0];
    const float* w_kv_a   = (const float*)d_in[1];
    const float* q_gamma  = (const float*)d_in[2];
    const float* w_qb     = (const float*)d_in[3];
    const float* kv_gamma = (const float*)d_in[4];
    const float* w_kvb    = (const float*)d_in[5];
    const float* w_o      = (const float*)d_in[6];
    float* out = (float*)d_out;

    char* p = (char*)d_ws;
    f16* hid_h   = (f16*)p;  p += (size_t)2048 * 2048 * 2;
    f16* wkva_t  = (f16*)p;  p += (size_t)2176 * 2048 * 2;
    f16* wqb_t   = (f16*)p;  p += (size_t)3072 * 1536 * 2;
    f16* wkvb_t  = (f16*)p;  p += (size_t)4096 * 512 * 2;
    f16* wo_t    = (f16*)p;  p += (size_t)2048 * 2048 * 2;
    float* fused = (float*)p; p += (size_t)2048 * FPAD * 4;
    f16* q_n     = (f16*)p;  p += (size_t)2048 * QL * 2;
    f16* qbuf    = (f16*)p;  p += (size_t)2048 * QB_N * 2;
    f16* kv_n    = (f16*)p;  p += (size_t)2048 * KL * 2;
    f16* kvbuf   = (f16*)p;  p += (size_t)2048 * KVB_N * 2;
    f16* attnb   = (f16*)p;  p += (size_t)2048 * 2048 * 2;
    f16* part_o  = (f16*)p;  p += (size_t)2 * 2048 * 2048 * 2;
    float* part_ml = (float*)p; p += (size_t)2 * NH * 2048 * 2 * 4;

    // aliases onto dead regions:
    //   kfull [16][2048][192] f16 (12.6 MB) <- hid_h (8.4) + start of wqb_t?  No:
    //     kfull needs 12.6 MB; hid_h(8.4)+wkva_t(8.9) span 17.3 MB contiguous ✓
    //   vt    [16][128][2048] f16 ( 8.4 MB) <- wkva_t region is inside kfull span!
    // -> put kfull at hid_h (uses hid_h + part of wkva_t: 12.6 MB of 17.3 ✓)
    //    and vt at the END of the wkva_t+wqb_t region: use wqb_t tail? wqb_t is
    //    alive until gemm_dual. Use 'fused' for vt BUT vt must not race kfull's
    //    read of fused -> with the fused post_k we instead place vt AFTER kfull
    //    span: offset 12.6 MB from hid_h start is inside wkva_t (17.3 MB span),
    //    leaving only 4.7 MB — not enough.  Solution: vt goes to part_o region
    //    (16.8 MB, dead until attn writes it... attn READS vt and WRITES part_o
    //    — conflict). Safe choice: vt overlays 'fused' but post_k keeps the
    //    ordering hazard-free by having vt blocks NOT alias the fused bytes
    //    kfull reads.  vt spans fused[0 .. 8.4 MB); kfull reads fused columns
    //    2048..2111 of each 2176-col row — bytes [row*8704 + 8192, row*8704+8448)
    //    for all 2048 rows, i.e. throughout [0, 17.8 MB). RACE would exist.
    // => allocate vt in fresh ws past part_ml instead (ws is large).
    f16* kfull = hid_h;
    f16* vt    = (f16*)p;   // fresh region, 8.4 MB

    dim3 blk(256);

    // prep: cvt + 4 weight transposes (one launch)
    prep_k<<<19200, blk, 0, stream>>>(hidden, hid_h, w_kv_a, wkva_t,
                                      w_qb, wqb_t, w_kvb, wkvb_t, w_o, wo_t);

    // 1. fused = hidden @ w_kv_a
    gemm_mfma<0><<<dim3(FPAD / 64, 16), blk, 0, stream>>>(
        hid_h, wkva_t, fused, FPAD, 2048);

    // 2. both RMSNorms (one launch)
    rmsnorm_k<<<4096, blk, 0, stream>>>(fused, q_gamma, kv_gamma, q_n, kv_n);

    // 3+4. q and kv up-projections fused (1792 blocks)
    gemm_dual<<<dim3(48 + 64, 16), blk, 0, stream>>>(
        q_n, wqb_t, qbuf, kv_n, wkvb_t, kvbuf);

    // 5. rope_q + kfull + vt (one launch; kfull overwrites hid_h/wkva_t which
    //    are dead after gemm1; vt in fresh region)
    post_k<<<15360, blk, 0, stream>>>(qbuf, kvbuf, fused, kfull, vt);

    // 6. attention (split-K=2) + combine
    attn_mfma_k<<<dim3(32, NH, 2), blk, 0, stream>>>(qbuf, kfull, vt, part_o, part_ml);
    attn_comb_k<<<2048, blk, 0, stream>>>(part_o, part_ml, attnb);

    // 7. out = attn @ w_o
    gemm_mfma<0><<<dim3(2048 / 64, 16), blk, 0, stream>>>(
        attnb, wo_t, out, 2048, 2048);
}